// Round 7
// baseline (231.379 us; speedup 1.0000x reference)
//
#include <hip/hip_runtime.h>
#include <hip/hip_bf16.h>
#include <stdint.h>

#define N_NODES 6144
#define IN_F    512
#define OUT_F   64
#define NH      8
#define ALPHA   0.2f
#define L2E     1.4426950408889634f
#define NTILES  (N_NODES / 64)   // 96

typedef __attribute__((ext_vector_type(8))) short bf16x8;
typedef __attribute__((ext_vector_type(8))) _Float16 f16x8;
typedef __attribute__((ext_vector_type(4))) float f32x4;

#define MFMA16B(a, b, c) __builtin_amdgcn_mfma_f32_16x16x32_bf16(a, b, c, 0, 0, 0)
#define MFMA16H(a, b, c) __builtin_amdgcn_mfma_f32_16x16x32_f16(a, b, c, 0, 0, 0)

__device__ __forceinline__ unsigned short f2bf(float f) {
    uint32_t u = __float_as_uint(f);
    u += 0x7fffu + ((u >> 16) & 1u);     // round-to-nearest-even
    return (unsigned short)(u >> 16);
}
__device__ __forceinline__ float bf2f(unsigned short h) {
    return __uint_as_float(((uint32_t)h) << 16);
}
__device__ __forceinline__ unsigned short f16b(float f) {
    union { _Float16 h; unsigned short u; } c;
    c.h = (_Float16)f;
    return c.u;
}
// monotone float<->uint encoding for atomicMax on floats (any sign)
__device__ __forceinline__ uint32_t encf(float x) {
    int i = __float_as_int(x);
    return (i >= 0) ? ((uint32_t)i | 0x80000000u) : ~(uint32_t)i;
}
__device__ __forceinline__ float decf(uint32_t u) {
    int i = (u & 0x80000000u) ? (int)(u & 0x7FFFFFFFu) : ~(int)u;
    return __int_as_float(i);
}

// ---------------------------------------------------------------------------
// W (f32 [8, 512, 64]) -> WT (bf16 [col=h*64+f][k=512]) hi + lo; init s2mu
__global__ __launch_bounds__(256) void k_convert_w(
    const float* __restrict__ W, unsigned short* __restrict__ wth,
    unsigned short* __restrict__ wtl, uint32_t* __restrict__ s2mu)
{
    int tid = blockIdx.x * 256 + threadIdx.x;        // 262144
    if (blockIdx.x == 0 && threadIdx.x < NH) s2mu[threadIdx.x] = 0u;
    int col = tid >> 9, k = tid & 511;
    int h = col >> 6, f = col & 63;
    float wv = W[(h * IN_F + k) * OUT_F + f];
    unsigned short hb = f2bf(wv);
    wth[tid] = hb;                                    // tid == col*512 + k
    wtl[tid] = f2bf(wv - bf2f(hb));
}

// ---------------------------------------------------------------------------
// adj (int32 [N,N]) -> TRANSPOSED bitmask: bmT[tile_cb][row] (u64)
__global__ __launch_bounds__(256) void k_pack_adj(
    const int* __restrict__ adj, unsigned long long* __restrict__ bmT)
{
    const int stride = gridDim.x * 256;
    for (int idx = blockIdx.x * 256 + threadIdx.x; idx < N_NODES * N_NODES;
         idx += stride) {
        unsigned long long b = __ballot(adj[idx] > 0);
        if ((threadIdx.x & 63) == 0) {
            int r = idx / N_NODES;
            int cb = (idx % N_NODES) >> 6;
            bmT[(size_t)cb * N_NODES + r] = b;
        }
    }
}

// ---------------------------------------------------------------------------
// Fused projection: reads f32 x (inline split-bf16 conversion), MFMA h=x@W,
// writes s1/s2, per-head s2-max via atomicMax, and writes hTF (f16,
// MFMA-B-fragment order) via a swizzled LDS tile. head = bid&7 (XCD-local).
__global__ __launch_bounds__(256) void k_proj(
    const float* __restrict__ x,
    const unsigned short* __restrict__ wth, const unsigned short* __restrict__ wtl,
    const float* __restrict__ a1, const float* __restrict__ a2,
    float* __restrict__ s1, float* __restrict__ s2,
    uint32_t* __restrict__ s2mu, unsigned short* __restrict__ hTF)
{
    __shared__ unsigned short hlds[64][64];          // 8 KB f16 tile, swizzled

    const int head = blockIdx.x & 7;
    const int rb = blockIdx.x >> 3;                  // 0..95
    const int w = threadIdx.x >> 6;
    const int lane = threadIdx.x & 63;
    const int r15 = lane & 15;
    const int g = lane >> 4;
    const int rowbase = rb * 64 + w * 16;
    const int rowA = rowbase + r15;

    f32x4 acc[4] = {};
    const float* xp = x + (size_t)rowA * IN_F + g * 8;
    const int colbase = head * 64;

#pragma unroll 4
    for (int i = 0; i < 16; ++i) {
        const int k0 = i * 32;
        float4 xa = *(const float4*)(xp + k0);
        float4 xb = *(const float4*)(xp + k0 + 4);
        float xv[8] = {xa.x, xa.y, xa.z, xa.w, xb.x, xb.y, xb.z, xb.w};
        union { unsigned short s[8]; bf16x8 v; } ah, al;
#pragma unroll
        for (int e = 0; e < 8; ++e) {
            unsigned short hb = f2bf(xv[e]);
            ah.s[e] = hb;
            al.s[e] = f2bf(xv[e] - bf2f(hb));
        }
#pragma unroll
        for (int ct = 0; ct < 4; ++ct) {
            size_t boff = (size_t)(colbase + ct * 16 + r15) * IN_F + k0 + g * 8;
            bf16x8 bh = *(const bf16x8*)(wth + boff);
            bf16x8 bl = *(const bf16x8*)(wtl + boff);
            acc[ct] = MFMA16B(ah.v, bh, acc[ct]);
            acc[ct] = MFMA16B(ah.v, bl, acc[ct]);
            acc[ct] = MFMA16B(al.v, bh, acc[ct]);
        }
    }

    // ---- s1/s2 (dot over f) ----
    float a1v[4], a2v[4];
#pragma unroll
    for (int ct = 0; ct < 4; ++ct) {
        a1v[ct] = a1[head * 64 + ct * 16 + r15];
        a2v[ct] = a2[head * 64 + ct * 16 + r15];
    }
    float sp1[4] = {0, 0, 0, 0}, sp2[4] = {0, 0, 0, 0};
#pragma unroll
    for (int ct = 0; ct < 4; ++ct)
#pragma unroll
        for (int j = 0; j < 4; ++j) {
            sp1[j] += acc[ct][j] * a1v[ct];
            sp2[j] += acc[ct][j] * a2v[ct];
        }
#pragma unroll
    for (int d = 1; d < 16; d <<= 1) {
#pragma unroll
        for (int j = 0; j < 4; ++j) {
            sp1[j] += __shfl_xor(sp1[j], d);
            sp2[j] += __shfl_xor(sp2[j], d);
        }
    }
    if (r15 == 0) {
#pragma unroll
        for (int j = 0; j < 4; ++j) {
            int n = rowbase + g * 4 + j;
            s1[head * N_NODES + n] = sp1[j];
            s2[head * N_NODES + n] = sp2[j];
        }
    }
    // per-head s2 max: wave-reduce then one atomic
    {
        float m = fmaxf(fmaxf(sp2[0], sp2[1]), fmaxf(sp2[2], sp2[3]));
        m = fmaxf(m, __shfl_xor(m, 16));
        m = fmaxf(m, __shfl_xor(m, 32));
        if (lane == 0) atomicMax(s2mu + head, encf(m));
    }

    // ---- stage f16 tile to LDS (chunk-XOR swizzle) ----
#pragma unroll
    for (int ct = 0; ct < 4; ++ct) {
        ushort4 pk;
        pk.x = f16b(acc[ct][0]);
        pk.y = f16b(acc[ct][1]);
        pk.z = f16b(acc[ct][2]);
        pk.w = f16b(acc[ct][3]);
        int f_l = ct * 16 + r15;
        int n0 = w * 16 + g * 4;
        int col = (((n0 >> 3) ^ (f_l & 7)) << 3) + (n0 & 7);
        *(ushort4*)&hlds[f_l][col] = pk;
    }
    __syncthreads();

    // ---- write MFMA-B fragments (f16) to hTF, coalesced ----
#pragma unroll
    for (int q = 0; q < 2; ++q) {
        int fid = 2 * w + q;                          // 0..7 = wk*4+ct
        int wk = fid >> 2, ct = fid & 3;
        int f_l = ct * 16 + (lane & 15);
        int nch = wk * 4 + (lane >> 4);
        int col = ((nch ^ (f_l & 7)) << 3);
        int4 v = *(const int4*)&hlds[f_l][col];
        size_t base = (((size_t)(head * 96 + rb)) * 8 + fid) * 512 + lane * 8;
        *(int4*)(hTF + base) = v;
    }
}

// ---------------------------------------------------------------------------
// packed-f16 tables (pre-scaled by s2max, all <= 1); also decode s2mf.
__global__ __launch_bounds__(256) void k_tables(
    const float* __restrict__ s2, const uint32_t* __restrict__ s2mu,
    uint32_t* __restrict__ epq, uint32_t* __restrict__ enq,
    float* __restrict__ s2mf)
{
    int i = blockIdx.x * 256 + threadIdx.x;          // H*N/2
    if (blockIdx.x == 0 && threadIdx.x < NH)
        s2mf[threadIdx.x] = decf(s2mu[threadIdx.x]);
    int h = (2 * i) / N_NODES;
    float sm = decf(s2mu[h]);
    float v0 = s2[2 * i] - sm, v1 = s2[2 * i + 1] - sm;
    uint32_t p0 = f16b(exp2f(v0 * L2E));
    uint32_t p1 = f16b(exp2f(v1 * L2E));
    uint32_t n0 = f16b(exp2f(ALPHA * v0 * L2E));
    uint32_t n1 = f16b(exp2f(ALPHA * v1 * L2E));
    epq[i] = p0 | (p1 << 16);
    enq[i] = n0 | (n1 << 16);
}

// ---------------------------------------------------------------------------
// packed-f16 P fragment: p2 = max(E1p2*ep2, E1n2*en2) masked via bfe sign-mask
__device__ __forceinline__ f16x8 mk_pa16(int4 ep, int4 en, uint32_t e1p2,
                                         uint32_t e1n2, uint32_t ms)
{
    const uint32_t epw[4] = {(uint32_t)ep.x, (uint32_t)ep.y, (uint32_t)ep.z,
                             (uint32_t)ep.w};
    const uint32_t enw[4] = {(uint32_t)en.x, (uint32_t)en.y, (uint32_t)en.z,
                             (uint32_t)en.w};
    union { uint32_t u[4]; f16x8 v; } r;
#define PAIR(J, B0, B1)                                                       \
    {                                                                         \
        uint32_t pa, pb, pm;                                                  \
        asm("v_pk_mul_f16 %0, %1, %2" : "=v"(pa) : "v"(e1p2), "v"(epw[J]));   \
        asm("v_pk_mul_f16 %0, %1, %2" : "=v"(pb) : "v"(e1n2), "v"(enw[J]));   \
        asm("v_pk_max_f16 %0, %1, %2" : "=v"(pm) : "v"(pa), "v"(pb));         \
        uint32_t mb0, mb1;                                                    \
        asm("v_bfe_i32 %0, %1, " #B0 ", 1" : "=v"(mb0) : "v"(ms));            \
        asm("v_bfe_i32 %0, %1, " #B1 ", 1" : "=v"(mb1) : "v"(ms));            \
        r.u[J] = pm & ((mb0 & 0x0000FFFFu) | (mb1 & 0xFFFF0000u));            \
    }
    PAIR(0, 0, 1)
    PAIR(1, 2, 3)
    PAIR(2, 4, 5)
    PAIR(3, 6, 7)
#undef PAIR
    return r.v;
}

struct Pf {                          // one-tile-ahead register prefetch
    int4 hb0, hb1, hb2, hb3;         // 4 H B-fragments (f16, this wave's kk)
    int4 ep, en;                     // packed-f16 tables (8 m)
    uint32_t m0, m1;                 // adjacency mask words per row-group
};

__device__ __forceinline__ f16x8 as_f16x8(int4 v) {
    union { int4 i; f16x8 h; } c;
    c.i = v;
    return c.h;
}

// ---------------------------------------------------------------------------
// Flash attention v6: barrier-free main loop, head = bid&7 so each XCD's L2
// holds exactly one head's hTF+tables (L2-resident); masks streamed with
// nontemporal loads. 4 waves = (row-half, m-half); LDS only for epilogue.
__global__ __launch_bounds__(256, 3) void k_flash(
    const unsigned short* __restrict__ hTF, const float* __restrict__ s1,
    const float* __restrict__ s2mf, const uint32_t* __restrict__ epq,
    const uint32_t* __restrict__ enq, const uint32_t* __restrict__ bmT32,
    float* __restrict__ out)
{
    __shared__ float fs[128 * 20];                   // 10 KB epilogue scratch

    const int head = blockIdx.x & 7;                 // == XCD id (round-robin)
    const int rb = blockIdx.x >> 3;
    const int tid = threadIdx.x;
    const int w = tid >> 6, lane = tid & 63, r15 = lane & 15, g = lane >> 4;
    const int w01 = w & 1;                           // row half
    const int wk = w >> 1;                           // m half (kk)
    const int shg = g * 8;                           // mask bit offset

    const int rA = rb * 64 + w01 * 32 + r15;
    const int rB = rA + 16;
    const float s2mh = s2mf[head];
    const float s1A = s1[head * N_NODES + rA];
    const float s1B = s1[head * N_NODES + rB];
    const float t0A = s1A + s2mh, t0B = s1B + s2mh;
    const float MrA = fmaxf(t0A, ALPHA * t0A);
    const float MrB = fmaxf(t0B, ALPHA * t0B);
    uint32_t E1pA2, E1nA2, E1pB2, E1nB2;
    {
        uint32_t a = f16b(exp2f((t0A - MrA) * L2E));
        uint32_t b = f16b(exp2f((ALPHA * t0A - MrA) * L2E));
        uint32_t c = f16b(exp2f((t0B - MrB) * L2E));
        uint32_t d = f16b(exp2f((ALPHA * t0B - MrB) * L2E));
        E1pA2 = a | (a << 16);
        E1nA2 = b | (b << 16);
        E1pB2 = c | (c << 16);
        E1nB2 = d | (d << 16);
    }

    const unsigned short* __restrict__ hbp =
        hTF + ((size_t)(head * 96) * 8 + wk * 4) * 512 + lane * 8;
    const uint32_t* __restrict__ epb = epq + head * 3072 + wk * 16 + g * 4;
    const uint32_t* __restrict__ enb = enq + head * 3072 + wk * 16 + g * 4;
    const size_t mbA = (size_t)rA * 2 + wk;          // + t*12288 per tile
    const size_t mbB = (size_t)rB * 2 + wk;

    f32x4 accA[4] = {}, accB[4] = {};
    f32x4 accSA = {}, accSB = {};
    const f16x8 vones = {(_Float16)1.0f, (_Float16)1.0f, (_Float16)1.0f,
                         (_Float16)1.0f, (_Float16)1.0f, (_Float16)1.0f,
                         (_Float16)1.0f, (_Float16)1.0f};

    auto loadPf = [&](int t, Pf& P) {
        const unsigned short* hp = hbp + (size_t)t * 4096;
        P.hb0 = *(const int4*)(hp);
        P.hb1 = *(const int4*)(hp + 512);
        P.hb2 = *(const int4*)(hp + 1024);
        P.hb3 = *(const int4*)(hp + 1536);
        P.ep = *(const int4*)(epb + t * 32);
        P.en = *(const int4*)(enb + t * 32);
        P.m0 = __builtin_nontemporal_load(bmT32 + mbA + (size_t)t * 12288);
        P.m1 = __builtin_nontemporal_load(bmT32 + mbB + (size_t)t * 12288);
    };
    auto compute = [&](Pf& C) {
        f16x8 paA = mk_pa16(C.ep, C.en, E1pA2, E1nA2, C.m0 >> shg);
        f16x8 paB = mk_pa16(C.ep, C.en, E1pB2, E1nB2, C.m1 >> shg);
        accSA = MFMA16H(paA, vones, accSA);
        accSB = MFMA16H(paB, vones, accSB);
        f16x8 h0 = as_f16x8(C.hb0), h1 = as_f16x8(C.hb1);
        f16x8 h2 = as_f16x8(C.hb2), h3 = as_f16x8(C.hb3);
        accA[0] = MFMA16H(paA, h0, accA[0]);
        accB[0] = MFMA16H(paB, h0, accB[0]);
        accA[1] = MFMA16H(paA, h1, accA[1]);
        accB[1] = MFMA16H(paB, h1, accB[1]);
        accA[2] = MFMA16H(paA, h2, accA[2]);
        accB[2] = MFMA16H(paB, h2, accB[2]);
        accA[3] = MFMA16H(paA, h3, accA[3]);
        accB[3] = MFMA16H(paB, h3, accB[3]);
    };

    Pf A, B;
    loadPf(0, A);
    for (int t = 0; t < NTILES; t += 2) {
        loadPf(t + 1, B);
        compute(A);
        if (t + 2 < NTILES) loadPf(t + 2, A);
        compute(B);
    }

    // ---- epilogue: combine the two m-half waves through LDS ----
    const int slot = w01 * 64 + lane;
    const int fcb = head * 64;
    const int nA = rb * 64 + w01 * 32 + g * 4;

    if (wk == 1) {
#pragma unroll
        for (int ct = 0; ct < 4; ++ct)
#pragma unroll
            for (int j = 0; j < 4; ++j) fs[slot * 20 + ct * 4 + j] = accA[ct][j];
#pragma unroll
        for (int j = 0; j < 4; ++j) fs[slot * 20 + 16 + j] = accSA[j];
    }
    __syncthreads();
    if (wk == 0) {
        float rinv[4];
#pragma unroll
        for (int j = 0; j < 4; ++j)
            rinv[j] = 1.0f / (accSA[j] + fs[slot * 20 + 16 + j]);
#pragma unroll
        for (int ct = 0; ct < 4; ++ct)
#pragma unroll
            for (int j = 0; j < 4; ++j) {
                float v = (accA[ct][j] + fs[slot * 20 + ct * 4 + j]) * rinv[j];
                v = (v > 0.f) ? v : (expf(v) - 1.f);
                out[(size_t)(nA + j) * 512 + fcb + ct * 16 + r15] = v;
            }
    }
    __syncthreads();
    if (wk == 1) {
#pragma unroll
        for (int ct = 0; ct < 4; ++ct)
#pragma unroll
            for (int j = 0; j < 4; ++j) fs[slot * 20 + ct * 4 + j] = accB[ct][j];
#pragma unroll
        for (int j = 0; j < 4; ++j) fs[slot * 20 + 16 + j] = accSB[j];
    }
    __syncthreads();
    if (wk == 0) {
        float rinv[4];
#pragma unroll
        for (int j = 0; j < 4; ++j)
            rinv[j] = 1.0f / (accSB[j] + fs[slot * 20 + 16 + j]);
#pragma unroll
        for (int ct = 0; ct < 4; ++ct)
#pragma unroll
            for (int j = 0; j < 4; ++j) {
                float v = (accB[ct][j] + fs[slot * 20 + ct * 4 + j]) * rinv[j];
                v = (v > 0.f) ? v : (expf(v) - 1.f);
                out[(size_t)(nA + 16 + j) * 512 + fcb + ct * 16 + r15] = v;
            }
    }
}

// ---------------------------------------------------------------------------
extern "C" void kernel_launch(void* const* d_in, const int* in_sizes, int n_in,
                              void* d_out, int out_size, void* d_ws, size_t ws_size,
                              hipStream_t stream)
{
    const float* x = (const float*)d_in[0];
    const int* adj = (const int*)d_in[1];
    const float* W = (const float*)d_in[2];
    const float* a1 = (const float*)d_in[3];
    const float* a2 = (const float*)d_in[4];
    float* out = (float*)d_out;

    char* ws = (char*)d_ws;
    size_t off = 0;
    auto take = [&](size_t bytes) {
        void* p = ws + off;
        off = (off + bytes + 255) & ~(size_t)255;
        return p;
    };
    unsigned short* wth = (unsigned short*)take((size_t)512 * 512 * 2);
    unsigned short* wtl = (unsigned short*)take((size_t)512 * 512 * 2);
    unsigned short* hTF = (unsigned short*)take((size_t)NH * 64 * N_NODES * 2);
    float* s1  = (float*)take((size_t)NH * N_NODES * 4);
    float* s2  = (float*)take((size_t)NH * N_NODES * 4);
    uint32_t* s2mu = (uint32_t*)take(256);
    float* s2mf = (float*)take(256);
    uint32_t* epq = (uint32_t*)take((size_t)NH * N_NODES / 2 * 4);
    uint32_t* enq = (uint32_t*)take((size_t)NH * N_NODES / 2 * 4);
    unsigned long long* bmT =
        (unsigned long long*)take((size_t)N_NODES * (N_NODES / 64) * 8);

    k_convert_w<<<dim3(1024), dim3(256), 0, stream>>>(W, wth, wtl, s2mu);
    k_pack_adj<<<dim3(2048), dim3(256), 0, stream>>>(adj, bmT);
    k_proj<<<dim3(NH * (N_NODES / 64)), dim3(256), 0, stream>>>(
        x, wth, wtl, a1, a2, s1, s2, s2mu, hTF);
    k_tables<<<dim3(NH * N_NODES / 2 / 256), dim3(256), 0, stream>>>(
        s2, s2mu, epq, enq, s2mf);
    k_flash<<<dim3(NH * NTILES), dim3(256), 0, stream>>>(
        hTF, s1, s2mf, epq, enq, (const uint32_t*)bmT, out);
}

// Round 8
// 187.318 us; speedup vs baseline: 1.2352x; 1.2352x over previous
//
#include <hip/hip_runtime.h>
#include <hip/hip_bf16.h>
#include <stdint.h>

#define N_NODES 6144
#define IN_F    512
#define OUT_F   64
#define NH      8
#define ALPHA   0.2f
#define L2E     1.4426950408889634f
#define NTILES  (N_NODES / 64)   // 96

typedef __attribute__((ext_vector_type(8))) short bf16x8;
typedef __attribute__((ext_vector_type(8))) _Float16 f16x8;
typedef __attribute__((ext_vector_type(4))) float f32x4;

#define MFMA16B(a, b, c) __builtin_amdgcn_mfma_f32_16x16x32_bf16(a, b, c, 0, 0, 0)
#define MFMA16H(a, b, c) __builtin_amdgcn_mfma_f32_16x16x32_f16(a, b, c, 0, 0, 0)

__device__ __forceinline__ unsigned short f2bf(float f) {
    uint32_t u = __float_as_uint(f);
    u += 0x7fffu + ((u >> 16) & 1u);     // round-to-nearest-even
    return (unsigned short)(u >> 16);
}
__device__ __forceinline__ float bf2f(unsigned short h) {
    return __uint_as_float(((uint32_t)h) << 16);
}
__device__ __forceinline__ unsigned short f16b(float f) {
    union { _Float16 h; unsigned short u; } c;
    c.h = (_Float16)f;
    return c.u;
}
// monotone float<->uint encoding for atomicMax on floats (any sign)
__device__ __forceinline__ uint32_t encf(float x) {
    int i = __float_as_int(x);
    return (i >= 0) ? ((uint32_t)i | 0x80000000u) : ~(uint32_t)i;
}
__device__ __forceinline__ float decf(uint32_t u) {
    int i = (u & 0x80000000u) ? (int)(u & 0x7FFFFFFFu) : ~(int)u;
    return __int_as_float(i);
}

// ---------------------------------------------------------------------------
// x (f32 [N, 512]) -> xh (bf16 hi) + xl (bf16 of residual), same layout.
// Done ONCE (x is shared by all 8 heads) — do not fuse into proj.
__global__ __launch_bounds__(256) void k_convert_x(
    const float* __restrict__ x, unsigned short* __restrict__ xh,
    unsigned short* __restrict__ xl)
{
    int i = blockIdx.x * 256 + threadIdx.x;          // per float4, 786432 total
    float4 v = ((const float4*)x)[i];
    float vv[4] = {v.x, v.y, v.z, v.w};
    unsigned short h4[4], l4[4];
#pragma unroll
    for (int c = 0; c < 4; ++c) {
        unsigned short hb = f2bf(vv[c]);
        h4[c] = hb;
        l4[c] = f2bf(vv[c] - bf2f(hb));
    }
    ((ushort4*)xh)[i] = make_ushort4(h4[0], h4[1], h4[2], h4[3]);
    ((ushort4*)xl)[i] = make_ushort4(l4[0], l4[1], l4[2], l4[3]);
}

// ---------------------------------------------------------------------------
// W (f32 [8,512,64]) -> MFMA-B-FRAGMENT order (hi + lo):
// wthF[(((h*16+i)*4+ct)*64+lane)*8+e] = bf16(W[h][i*32+(lane>>4)*8+e][ct*16+(lane&15)])
// so proj's B loads are 16B/lane coalesced. Also init s2mu.
__global__ __launch_bounds__(256) void k_convert_w(
    const float* __restrict__ W, unsigned short* __restrict__ wthF,
    unsigned short* __restrict__ wtlF, uint32_t* __restrict__ s2mu)
{
    int tid = blockIdx.x * 256 + threadIdx.x;        // 32768
    if (blockIdx.x == 0 && threadIdx.x < NH) s2mu[threadIdx.x] = 0u;
    int lane = tid & 63;
    int rest = tid >> 6;
    int ct = rest & 3;
    int i = (rest >> 2) & 15;
    int h = rest >> 6;
    int f = ct * 16 + (lane & 15);
    int k0 = i * 32 + (lane >> 4) * 8;
    unsigned short oh[8], ol[8];
#pragma unroll
    for (int e = 0; e < 8; ++e) {
        float wv = W[((size_t)h * IN_F + k0 + e) * OUT_F + f];
        unsigned short hb = f2bf(wv);
        oh[e] = hb;
        ol[e] = f2bf(wv - bf2f(hb));
    }
    ushort4* dh = (ushort4*)(wthF + (size_t)tid * 8);
    dh[0] = make_ushort4(oh[0], oh[1], oh[2], oh[3]);
    dh[1] = make_ushort4(oh[4], oh[5], oh[6], oh[7]);
    ushort4* dl = (ushort4*)(wtlF + (size_t)tid * 8);
    dl[0] = make_ushort4(ol[0], ol[1], ol[2], ol[3]);
    dl[1] = make_ushort4(ol[4], ol[5], ol[6], ol[7]);
}

// ---------------------------------------------------------------------------
// adj (int32 [N,N]) -> TRANSPOSED bitmask: bmT[tile_cb][row] (u64)
__global__ __launch_bounds__(256) void k_pack_adj(
    const int* __restrict__ adj, unsigned long long* __restrict__ bmT)
{
    const int stride = gridDim.x * 256;
    for (int idx = blockIdx.x * 256 + threadIdx.x; idx < N_NODES * N_NODES;
         idx += stride) {
        unsigned long long b = __ballot(adj[idx] > 0);
        if ((threadIdx.x & 63) == 0) {
            int r = idx / N_NODES;
            int cb = (idx % N_NODES) >> 6;
            bmT[(size_t)cb * N_NODES + r] = b;
        }
    }
}

// ---------------------------------------------------------------------------
// Projection: h = x @ W (split-bf16, fragment-ordered W, fully coalesced);
// writes s1/s2, per-head s2max (atomicMax), and hTF (f16 MFMA-B-fragment
// order) via swizzled LDS transpose. head = bid&7 (XCD-local W fragments).
__global__ __launch_bounds__(256) void k_proj(
    const unsigned short* __restrict__ xh, const unsigned short* __restrict__ xl,
    const unsigned short* __restrict__ wthF, const unsigned short* __restrict__ wtlF,
    const float* __restrict__ a1, const float* __restrict__ a2,
    float* __restrict__ s1, float* __restrict__ s2,
    uint32_t* __restrict__ s2mu, unsigned short* __restrict__ hTF)
{
    __shared__ unsigned short hlds[64][64];          // 8 KB f16 tile, swizzled

    const int head = blockIdx.x & 7;
    const int rb = blockIdx.x >> 3;                  // 0..95
    const int w = threadIdx.x >> 6;
    const int lane = threadIdx.x & 63;
    const int r15 = lane & 15;
    const int g = lane >> 4;
    const int rowbase = rb * 64 + w * 16;
    const int rowA = rowbase + r15;

    f32x4 acc[4] = {};
    const unsigned short* xhp = xh + (size_t)rowA * IN_F + g * 8;
    const unsigned short* xlp = xl + (size_t)rowA * IN_F + g * 8;
    const unsigned short* wb = wthF + ((size_t)head * 16 * 4 * 64) * 8 + lane * 8;
    const unsigned short* wl = wtlF + ((size_t)head * 16 * 4 * 64) * 8 + lane * 8;

#pragma unroll 4
    for (int i = 0; i < 16; ++i) {
        const int k0 = i * 32;
        bf16x8 ah = *(const bf16x8*)(xhp + k0);
        bf16x8 al = *(const bf16x8*)(xlp + k0);
#pragma unroll
        for (int ct = 0; ct < 4; ++ct) {
            const size_t fo = (size_t)(i * 4 + ct) * 512;
            bf16x8 bh = *(const bf16x8*)(wb + fo);
            bf16x8 bl = *(const bf16x8*)(wl + fo);
            acc[ct] = MFMA16B(ah, bh, acc[ct]);
            acc[ct] = MFMA16B(ah, bl, acc[ct]);
            acc[ct] = MFMA16B(al, bh, acc[ct]);
        }
    }

    // ---- s1/s2 (dot over f) ----
    float a1v[4], a2v[4];
#pragma unroll
    for (int ct = 0; ct < 4; ++ct) {
        a1v[ct] = a1[head * 64 + ct * 16 + r15];
        a2v[ct] = a2[head * 64 + ct * 16 + r15];
    }
    float sp1[4] = {0, 0, 0, 0}, sp2[4] = {0, 0, 0, 0};
#pragma unroll
    for (int ct = 0; ct < 4; ++ct)
#pragma unroll
        for (int j = 0; j < 4; ++j) {
            sp1[j] += acc[ct][j] * a1v[ct];
            sp2[j] += acc[ct][j] * a2v[ct];
        }
#pragma unroll
    for (int d = 1; d < 16; d <<= 1) {
#pragma unroll
        for (int j = 0; j < 4; ++j) {
            sp1[j] += __shfl_xor(sp1[j], d);
            sp2[j] += __shfl_xor(sp2[j], d);
        }
    }
    if (r15 == 0) {
#pragma unroll
        for (int j = 0; j < 4; ++j) {
            int n = rowbase + g * 4 + j;
            s1[head * N_NODES + n] = sp1[j];
            s2[head * N_NODES + n] = sp2[j];
        }
    }
    {   // per-head s2 max: wave-reduce then one atomic
        float m = fmaxf(fmaxf(sp2[0], sp2[1]), fmaxf(sp2[2], sp2[3]));
        m = fmaxf(m, __shfl_xor(m, 16));
        m = fmaxf(m, __shfl_xor(m, 32));
        if (lane == 0) atomicMax(s2mu + head, encf(m));
    }

    // ---- stage f16 tile to LDS (chunk-XOR swizzle) ----
#pragma unroll
    for (int ct = 0; ct < 4; ++ct) {
        ushort4 pk;
        pk.x = f16b(acc[ct][0]);
        pk.y = f16b(acc[ct][1]);
        pk.z = f16b(acc[ct][2]);
        pk.w = f16b(acc[ct][3]);
        int f_l = ct * 16 + r15;
        int n0 = w * 16 + g * 4;
        int col = (((n0 >> 3) ^ (f_l & 7)) << 3) + (n0 & 7);
        *(ushort4*)&hlds[f_l][col] = pk;
    }
    __syncthreads();

    // ---- write MFMA-B fragments (f16) to hTF, coalesced ----
#pragma unroll
    for (int q = 0; q < 2; ++q) {
        int fid = 2 * w + q;                          // 0..7 = wk*4+ct
        int wk = fid >> 2, ct = fid & 3;
        int f_l = ct * 16 + (lane & 15);
        int nch = wk * 4 + (lane >> 4);
        int col = ((nch ^ (f_l & 7)) << 3);
        int4 v = *(const int4*)&hlds[f_l][col];
        size_t base = (((size_t)(head * 96 + rb)) * 8 + fid) * 512 + lane * 8;
        *(int4*)(hTF + base) = v;
    }
}

// ---------------------------------------------------------------------------
// packed-f16 tables (pre-scaled by s2max, all <= 1); also decode s2mf.
__global__ __launch_bounds__(256) void k_tables(
    const float* __restrict__ s2, const uint32_t* __restrict__ s2mu,
    uint32_t* __restrict__ epq, uint32_t* __restrict__ enq,
    float* __restrict__ s2mf)
{
    int i = blockIdx.x * 256 + threadIdx.x;          // H*N/2
    if (blockIdx.x == 0 && threadIdx.x < NH)
        s2mf[threadIdx.x] = decf(s2mu[threadIdx.x]);
    int h = (2 * i) / N_NODES;
    float sm = decf(s2mu[h]);
    float v0 = s2[2 * i] - sm, v1 = s2[2 * i + 1] - sm;
    uint32_t p0 = f16b(exp2f(v0 * L2E));
    uint32_t p1 = f16b(exp2f(v1 * L2E));
    uint32_t n0 = f16b(exp2f(ALPHA * v0 * L2E));
    uint32_t n1 = f16b(exp2f(ALPHA * v1 * L2E));
    epq[i] = p0 | (p1 << 16);
    enq[i] = n0 | (n1 << 16);
}

// ---------------------------------------------------------------------------
// packed-f16 P fragment: p2 = max(E1p2*ep2, E1n2*en2) masked via bfe sign-mask
__device__ __forceinline__ f16x8 mk_pa16(int4 ep, int4 en, uint32_t e1p2,
                                         uint32_t e1n2, uint32_t ms)
{
    const uint32_t epw[4] = {(uint32_t)ep.x, (uint32_t)ep.y, (uint32_t)ep.z,
                             (uint32_t)ep.w};
    const uint32_t enw[4] = {(uint32_t)en.x, (uint32_t)en.y, (uint32_t)en.z,
                             (uint32_t)en.w};
    union { uint32_t u[4]; f16x8 v; } r;
#define PAIR(J, B0, B1)                                                       \
    {                                                                         \
        uint32_t pa, pb, pm;                                                  \
        asm("v_pk_mul_f16 %0, %1, %2" : "=v"(pa) : "v"(e1p2), "v"(epw[J]));   \
        asm("v_pk_mul_f16 %0, %1, %2" : "=v"(pb) : "v"(e1n2), "v"(enw[J]));   \
        asm("v_pk_max_f16 %0, %1, %2" : "=v"(pm) : "v"(pa), "v"(pb));         \
        uint32_t mb0, mb1;                                                    \
        asm("v_bfe_i32 %0, %1, " #B0 ", 1" : "=v"(mb0) : "v"(ms));            \
        asm("v_bfe_i32 %0, %1, " #B1 ", 1" : "=v"(mb1) : "v"(ms));            \
        r.u[J] = pm & ((mb0 & 0x0000FFFFu) | (mb1 & 0xFFFF0000u));            \
    }
    PAIR(0, 0, 1)
    PAIR(1, 2, 3)
    PAIR(2, 4, 5)
    PAIR(3, 6, 7)
#undef PAIR
    return r.v;
}

struct Pf {                          // one-tile-ahead register prefetch
    int4 hb0, hb1, hb2, hb3;         // 4 H B-fragments (f16, this wave's kk)
    int4 ep, en;                     // packed-f16 tables (8 m)
    uint32_t m0, m1;                 // adjacency mask words per row-group
};

__device__ __forceinline__ f16x8 as_f16x8(int4 v) {
    union { int4 i; f16x8 h; } c;
    c.i = v;
    return c.h;
}

// ---------------------------------------------------------------------------
// Flash attention v7: barrier-free main loop, head = bid&7 (XCD-local hTF +
// tables in L2). Masks via NORMAL loads (nt in R7 put L3 latency on the
// critical prefetch path — reverted). 4 waves = (row-half, m-half).
__global__ __launch_bounds__(256, 3) void k_flash(
    const unsigned short* __restrict__ hTF, const float* __restrict__ s1,
    const float* __restrict__ s2mf, const uint32_t* __restrict__ epq,
    const uint32_t* __restrict__ enq, const uint32_t* __restrict__ bmT32,
    float* __restrict__ out)
{
    __shared__ float fs[128 * 20];                   // 10 KB epilogue scratch

    const int head = blockIdx.x & 7;                 // == XCD id (round-robin)
    const int rb = blockIdx.x >> 3;
    const int tid = threadIdx.x;
    const int w = tid >> 6, lane = tid & 63, r15 = lane & 15, g = lane >> 4;
    const int w01 = w & 1;                           // row half
    const int wk = w >> 1;                           // m half (kk)
    const int shg = g * 8;                           // mask bit offset

    const int rA = rb * 64 + w01 * 32 + r15;
    const int rB = rA + 16;
    const float s2mh = s2mf[head];
    const float s1A = s1[head * N_NODES + rA];
    const float s1B = s1[head * N_NODES + rB];
    const float t0A = s1A + s2mh, t0B = s1B + s2mh;
    const float MrA = fmaxf(t0A, ALPHA * t0A);
    const float MrB = fmaxf(t0B, ALPHA * t0B);
    uint32_t E1pA2, E1nA2, E1pB2, E1nB2;
    {
        uint32_t a = f16b(exp2f((t0A - MrA) * L2E));
        uint32_t b = f16b(exp2f((ALPHA * t0A - MrA) * L2E));
        uint32_t c = f16b(exp2f((t0B - MrB) * L2E));
        uint32_t d = f16b(exp2f((ALPHA * t0B - MrB) * L2E));
        E1pA2 = a | (a << 16);
        E1nA2 = b | (b << 16);
        E1pB2 = c | (c << 16);
        E1nB2 = d | (d << 16);
    }

    const unsigned short* __restrict__ hbp =
        hTF + ((size_t)(head * 96) * 8 + wk * 4) * 512 + lane * 8;
    const uint32_t* __restrict__ epb = epq + head * 3072 + wk * 16 + g * 4;
    const uint32_t* __restrict__ enb = enq + head * 3072 + wk * 16 + g * 4;
    const size_t mbA = (size_t)rA * 2 + wk;          // + t*12288 per tile
    const size_t mbB = (size_t)rB * 2 + wk;

    f32x4 accA[4] = {}, accB[4] = {};
    f32x4 accSA = {}, accSB = {};
    const f16x8 vones = {(_Float16)1.0f, (_Float16)1.0f, (_Float16)1.0f,
                         (_Float16)1.0f, (_Float16)1.0f, (_Float16)1.0f,
                         (_Float16)1.0f, (_Float16)1.0f};

    auto loadPf = [&](int t, Pf& P) {
        const unsigned short* hp = hbp + (size_t)t * 4096;
        P.hb0 = *(const int4*)(hp);
        P.hb1 = *(const int4*)(hp + 512);
        P.hb2 = *(const int4*)(hp + 1024);
        P.hb3 = *(const int4*)(hp + 1536);
        P.ep = *(const int4*)(epb + t * 32);
        P.en = *(const int4*)(enb + t * 32);
        P.m0 = bmT32[mbA + (size_t)t * 12288];
        P.m1 = bmT32[mbB + (size_t)t * 12288];
    };
    auto compute = [&](Pf& C) {
        f16x8 paA = mk_pa16(C.ep, C.en, E1pA2, E1nA2, C.m0 >> shg);
        f16x8 paB = mk_pa16(C.ep, C.en, E1pB2, E1nB2, C.m1 >> shg);
        accSA = MFMA16H(paA, vones, accSA);
        accSB = MFMA16H(paB, vones, accSB);
        f16x8 h0 = as_f16x8(C.hb0), h1 = as_f16x8(C.hb1);
        f16x8 h2 = as_f16x8(C.hb2), h3 = as_f16x8(C.hb3);
        accA[0] = MFMA16H(paA, h0, accA[0]);
        accB[0] = MFMA16H(paB, h0, accB[0]);
        accA[1] = MFMA16H(paA, h1, accA[1]);
        accB[1] = MFMA16H(paB, h1, accB[1]);
        accA[2] = MFMA16H(paA, h2, accA[2]);
        accB[2] = MFMA16H(paB, h2, accB[2]);
        accA[3] = MFMA16H(paA, h3, accA[3]);
        accB[3] = MFMA16H(paB, h3, accB[3]);
    };

    Pf A, B;
    loadPf(0, A);
    for (int t = 0; t < NTILES; t += 2) {
        loadPf(t + 1, B);
        compute(A);
        if (t + 2 < NTILES) loadPf(t + 2, A);
        compute(B);
    }

    // ---- epilogue: combine the two m-half waves through LDS ----
    const int slot = w01 * 64 + lane;
    const int fcb = head * 64;
    const int nA = rb * 64 + w01 * 32 + g * 4;

    if (wk == 1) {
#pragma unroll
        for (int ct = 0; ct < 4; ++ct)
#pragma unroll
            for (int j = 0; j < 4; ++j) fs[slot * 20 + ct * 4 + j] = accA[ct][j];
#pragma unroll
        for (int j = 0; j < 4; ++j) fs[slot * 20 + 16 + j] = accSA[j];
    }
    __syncthreads();
    if (wk == 0) {
        float rinv[4];
#pragma unroll
        for (int j = 0; j < 4; ++j)
            rinv[j] = 1.0f / (accSA[j] + fs[slot * 20 + 16 + j]);
#pragma unroll
        for (int ct = 0; ct < 4; ++ct)
#pragma unroll
            for (int j = 0; j < 4; ++j) {
                float v = (accA[ct][j] + fs[slot * 20 + ct * 4 + j]) * rinv[j];
                v = (v > 0.f) ? v : (expf(v) - 1.f);
                out[(size_t)(nA + j) * 512 + fcb + ct * 16 + r15] = v;
            }
    }
    __syncthreads();
    if (wk == 1) {
#pragma unroll
        for (int ct = 0; ct < 4; ++ct)
#pragma unroll
            for (int j = 0; j < 4; ++j) fs[slot * 20 + ct * 4 + j] = accB[ct][j];
#pragma unroll
        for (int j = 0; j < 4; ++j) fs[slot * 20 + 16 + j] = accSB[j];
    }
    __syncthreads();
    if (wk == 0) {
        float rinv[4];
#pragma unroll
        for (int j = 0; j < 4; ++j)
            rinv[j] = 1.0f / (accSB[j] + fs[slot * 20 + 16 + j]);
#pragma unroll
        for (int ct = 0; ct < 4; ++ct)
#pragma unroll
            for (int j = 0; j < 4; ++j) {
                float v = (accB[ct][j] + fs[slot * 20 + ct * 4 + j]) * rinv[j];
                v = (v > 0.f) ? v : (expf(v) - 1.f);
                out[(size_t)(nA + 16 + j) * 512 + fcb + ct * 16 + r15] = v;
            }
    }
}

// ---------------------------------------------------------------------------
extern "C" void kernel_launch(void* const* d_in, const int* in_sizes, int n_in,
                              void* d_out, int out_size, void* d_ws, size_t ws_size,
                              hipStream_t stream)
{
    const float* x = (const float*)d_in[0];
    const int* adj = (const int*)d_in[1];
    const float* W = (const float*)d_in[2];
    const float* a1 = (const float*)d_in[3];
    const float* a2 = (const float*)d_in[4];
    float* out = (float*)d_out;

    char* ws = (char*)d_ws;
    size_t off = 0;
    auto take = [&](size_t bytes) {
        void* p = ws + off;
        off = (off + bytes + 255) & ~(size_t)255;
        return p;
    };
    unsigned short* xh   = (unsigned short*)take((size_t)N_NODES * IN_F * 2);
    unsigned short* xl   = (unsigned short*)take((size_t)N_NODES * IN_F * 2);
    unsigned short* wthF = (unsigned short*)take((size_t)512 * 512 * 2);
    unsigned short* wtlF = (unsigned short*)take((size_t)512 * 512 * 2);
    unsigned short* hTF  = (unsigned short*)take((size_t)NH * 64 * N_NODES * 2);
    float* s1  = (float*)take((size_t)NH * N_NODES * 4);
    float* s2  = (float*)take((size_t)NH * N_NODES * 4);
    uint32_t* s2mu = (uint32_t*)take(256);
    float* s2mf = (float*)take(256);
    uint32_t* epq = (uint32_t*)take((size_t)NH * N_NODES / 2 * 4);
    uint32_t* enq = (uint32_t*)take((size_t)NH * N_NODES / 2 * 4);
    unsigned long long* bmT =
        (unsigned long long*)take((size_t)N_NODES * (N_NODES / 64) * 8);

    k_convert_x<<<dim3((N_NODES * IN_F / 4) / 256), dim3(256), 0, stream>>>(x, xh, xl);
    k_convert_w<<<dim3(128), dim3(256), 0, stream>>>(W, wthF, wtlF, s2mu);
    k_pack_adj<<<dim3(2048), dim3(256), 0, stream>>>(adj, bmT);
    k_proj<<<dim3(NH * (N_NODES / 64)), dim3(256), 0, stream>>>(
        xh, xl, wthF, wtlF, a1, a2, s1, s2, s2mu, hTF);
    k_tables<<<dim3(NH * N_NODES / 2 / 256), dim3(256), 0, stream>>>(
        s2, s2mu, epq, enq, s2mf);
    k_flash<<<dim3(NH * NTILES), dim3(256), 0, stream>>>(
        hTF, s1, s2mf, epq, enq, (const uint32_t*)bmT, out);
}

// Round 9
// 168.627 us; speedup vs baseline: 1.3721x; 1.1108x over previous
//
#include <hip/hip_runtime.h>
#include <hip/hip_bf16.h>
#include <stdint.h>

#define N_NODES 6144
#define IN_F    512
#define OUT_F   64
#define NH      8
#define ALPHA   0.2f
#define L2E     1.4426950408889634f
#define NTILES  (N_NODES / 64)   // 96

typedef __attribute__((ext_vector_type(8))) short bf16x8;
typedef __attribute__((ext_vector_type(8))) _Float16 f16x8;
typedef __attribute__((ext_vector_type(4))) float f32x4;

#define MFMA16B(a, b, c) __builtin_amdgcn_mfma_f32_16x16x32_bf16(a, b, c, 0, 0, 0)
#define MFMA16H(a, b, c) __builtin_amdgcn_mfma_f32_16x16x32_f16(a, b, c, 0, 0, 0)

__device__ __forceinline__ unsigned short f2bf(float f) {
    uint32_t u = __float_as_uint(f);
    u += 0x7fffu + ((u >> 16) & 1u);     // round-to-nearest-even
    return (unsigned short)(u >> 16);
}
__device__ __forceinline__ float bf2f(unsigned short h) {
    return __uint_as_float(((uint32_t)h) << 16);
}
__device__ __forceinline__ unsigned short f16b(float f) {
    union { _Float16 h; unsigned short u; } c;
    c.h = (_Float16)f;
    return c.u;
}
// monotone float<->uint encoding for atomicMax on floats (any sign)
__device__ __forceinline__ uint32_t encf(float x) {
    int i = __float_as_int(x);
    return (i >= 0) ? ((uint32_t)i | 0x80000000u) : ~(uint32_t)i;
}
__device__ __forceinline__ float decf(uint32_t u) {
    int i = (u & 0x80000000u) ? (int)(u & 0x7FFFFFFFu) : ~(int)u;
    return __int_as_float(i);
}

// ---------------------------------------------------------------------------
// Fused prep: [0,2048)   pack_adj  (HBM long pole, launched first)
//             [2048,5120) convert_x
//             [5120,5248) convert_w (fragment-order) + s2mu init
__global__ __launch_bounds__(256) void k_prep(
    const float* __restrict__ x, unsigned short* __restrict__ xh,
    unsigned short* __restrict__ xl,
    const float* __restrict__ W, unsigned short* __restrict__ wthF,
    unsigned short* __restrict__ wtlF, uint32_t* __restrict__ s2mu,
    const int* __restrict__ adj, unsigned long long* __restrict__ bmT)
{
    const int bid = blockIdx.x;
    if (bid < 2048) {
        // ---- pack_adj: adj -> transposed bitmask bmT[cb][row] ----
        const int stride = 2048 * 256;
        for (int idx = bid * 256 + threadIdx.x; idx < N_NODES * N_NODES;
             idx += stride) {
            unsigned long long b = __ballot(adj[idx] > 0);
            if ((threadIdx.x & 63) == 0) {
                int r = idx / N_NODES;
                int cb = (idx % N_NODES) >> 6;
                bmT[(size_t)cb * N_NODES + r] = b;
            }
        }
    } else if (bid < 5120) {
        // ---- convert_x: f32 -> split bf16 (hi+lo), once for all heads ----
        int i = (bid - 2048) * 256 + threadIdx.x;    // per float4, 786432
        float4 v = ((const float4*)x)[i];
        float vv[4] = {v.x, v.y, v.z, v.w};
        unsigned short h4[4], l4[4];
#pragma unroll
        for (int c = 0; c < 4; ++c) {
            unsigned short hb = f2bf(vv[c]);
            h4[c] = hb;
            l4[c] = f2bf(vv[c] - bf2f(hb));
        }
        ((ushort4*)xh)[i] = make_ushort4(h4[0], h4[1], h4[2], h4[3]);
        ((ushort4*)xl)[i] = make_ushort4(l4[0], l4[1], l4[2], l4[3]);
    } else {
        // ---- convert_w -> MFMA-B-fragment order (hi+lo); init s2mu ----
        int tid = (bid - 5120) * 256 + threadIdx.x;  // 32768
        if (bid == 5120 && threadIdx.x < NH) s2mu[threadIdx.x] = 0u;
        int lane = tid & 63;
        int rest = tid >> 6;
        int ct = rest & 3;
        int i = (rest >> 2) & 15;
        int h = rest >> 6;
        int f = ct * 16 + (lane & 15);
        int k0 = i * 32 + (lane >> 4) * 8;
        unsigned short oh[8], ol[8];
#pragma unroll
        for (int e = 0; e < 8; ++e) {
            float wv = W[((size_t)h * IN_F + k0 + e) * OUT_F + f];
            unsigned short hb = f2bf(wv);
            oh[e] = hb;
            ol[e] = f2bf(wv - bf2f(hb));
        }
        ushort4* dh = (ushort4*)(wthF + (size_t)tid * 8);
        dh[0] = make_ushort4(oh[0], oh[1], oh[2], oh[3]);
        dh[1] = make_ushort4(oh[4], oh[5], oh[6], oh[7]);
        ushort4* dl = (ushort4*)(wtlF + (size_t)tid * 8);
        dl[0] = make_ushort4(ol[0], ol[1], ol[2], ol[3]);
        dl[1] = make_ushort4(ol[4], ol[5], ol[6], ol[7]);
    }
}

// ---------------------------------------------------------------------------
// Projection: h = x @ W (split-bf16, fragment-ordered W, fully coalesced);
// writes s1/s2, per-head s2max (atomicMax), and hTF (f16 MFMA-B-fragment
// order) via swizzled LDS transpose. head = bid&7 (XCD-local W fragments).
__global__ __launch_bounds__(256) void k_proj(
    const unsigned short* __restrict__ xh, const unsigned short* __restrict__ xl,
    const unsigned short* __restrict__ wthF, const unsigned short* __restrict__ wtlF,
    const float* __restrict__ a1, const float* __restrict__ a2,
    float* __restrict__ s1, float* __restrict__ s2,
    uint32_t* __restrict__ s2mu, unsigned short* __restrict__ hTF)
{
    __shared__ unsigned short hlds[64][64];          // 8 KB f16 tile, swizzled

    const int head = blockIdx.x & 7;
    const int rb = blockIdx.x >> 3;                  // 0..95
    const int w = threadIdx.x >> 6;
    const int lane = threadIdx.x & 63;
    const int r15 = lane & 15;
    const int g = lane >> 4;
    const int rowbase = rb * 64 + w * 16;
    const int rowA = rowbase + r15;

    f32x4 acc[4] = {};
    const unsigned short* xhp = xh + (size_t)rowA * IN_F + g * 8;
    const unsigned short* xlp = xl + (size_t)rowA * IN_F + g * 8;
    const unsigned short* wb = wthF + ((size_t)head * 16 * 4 * 64) * 8 + lane * 8;
    const unsigned short* wl = wtlF + ((size_t)head * 16 * 4 * 64) * 8 + lane * 8;

#pragma unroll 4
    for (int i = 0; i < 16; ++i) {
        const int k0 = i * 32;
        bf16x8 ah = *(const bf16x8*)(xhp + k0);
        bf16x8 al = *(const bf16x8*)(xlp + k0);
#pragma unroll
        for (int ct = 0; ct < 4; ++ct) {
            const size_t fo = (size_t)(i * 4 + ct) * 512;
            bf16x8 bh = *(const bf16x8*)(wb + fo);
            bf16x8 bl = *(const bf16x8*)(wl + fo);
            acc[ct] = MFMA16B(ah, bh, acc[ct]);
            acc[ct] = MFMA16B(ah, bl, acc[ct]);
            acc[ct] = MFMA16B(al, bh, acc[ct]);
        }
    }

    // ---- s1/s2 (dot over f) ----
    float a1v[4], a2v[4];
#pragma unroll
    for (int ct = 0; ct < 4; ++ct) {
        a1v[ct] = a1[head * 64 + ct * 16 + r15];
        a2v[ct] = a2[head * 64 + ct * 16 + r15];
    }
    float sp1[4] = {0, 0, 0, 0}, sp2[4] = {0, 0, 0, 0};
#pragma unroll
    for (int ct = 0; ct < 4; ++ct)
#pragma unroll
        for (int j = 0; j < 4; ++j) {
            sp1[j] += acc[ct][j] * a1v[ct];
            sp2[j] += acc[ct][j] * a2v[ct];
        }
#pragma unroll
    for (int d = 1; d < 16; d <<= 1) {
#pragma unroll
        for (int j = 0; j < 4; ++j) {
            sp1[j] += __shfl_xor(sp1[j], d);
            sp2[j] += __shfl_xor(sp2[j], d);
        }
    }
    if (r15 == 0) {
#pragma unroll
        for (int j = 0; j < 4; ++j) {
            int n = rowbase + g * 4 + j;
            s1[head * N_NODES + n] = sp1[j];
            s2[head * N_NODES + n] = sp2[j];
        }
    }
    {   // per-head s2 max: wave-reduce then one atomic
        float m = fmaxf(fmaxf(sp2[0], sp2[1]), fmaxf(sp2[2], sp2[3]));
        m = fmaxf(m, __shfl_xor(m, 16));
        m = fmaxf(m, __shfl_xor(m, 32));
        if (lane == 0) atomicMax(s2mu + head, encf(m));
    }

    // ---- stage f16 tile to LDS (chunk-XOR swizzle) ----
#pragma unroll
    for (int ct = 0; ct < 4; ++ct) {
        ushort4 pk;
        pk.x = f16b(acc[ct][0]);
        pk.y = f16b(acc[ct][1]);
        pk.z = f16b(acc[ct][2]);
        pk.w = f16b(acc[ct][3]);
        int f_l = ct * 16 + r15;
        int n0 = w * 16 + g * 4;
        int col = (((n0 >> 3) ^ (f_l & 7)) << 3) + (n0 & 7);
        *(ushort4*)&hlds[f_l][col] = pk;
    }
    __syncthreads();

    // ---- write MFMA-B fragments (f16) to hTF, coalesced ----
#pragma unroll
    for (int q = 0; q < 2; ++q) {
        int fid = 2 * w + q;                          // 0..7 = wk*4+ct
        int wk = fid >> 2, ct = fid & 3;
        int f_l = ct * 16 + (lane & 15);
        int nch = wk * 4 + (lane >> 4);
        int col = ((nch ^ (f_l & 7)) << 3);
        int4 v = *(const int4*)&hlds[f_l][col];
        size_t base = (((size_t)(head * 96 + rb)) * 8 + fid) * 512 + lane * 8;
        *(int4*)(hTF + base) = v;
    }
}

// ---------------------------------------------------------------------------
// packed-f16 P fragment: p2 = max(E1p2*ep2, E1n2*en2) masked via bfe sign-mask
__device__ __forceinline__ f16x8 mk_pa16(int4 ep, int4 en, uint32_t e1p2,
                                         uint32_t e1n2, uint32_t ms)
{
    const uint32_t epw[4] = {(uint32_t)ep.x, (uint32_t)ep.y, (uint32_t)ep.z,
                             (uint32_t)ep.w};
    const uint32_t enw[4] = {(uint32_t)en.x, (uint32_t)en.y, (uint32_t)en.z,
                             (uint32_t)en.w};
    union { uint32_t u[4]; f16x8 v; } r;
#define PAIR(J, B0, B1)                                                       \
    {                                                                         \
        uint32_t pa, pb, pm;                                                  \
        asm("v_pk_mul_f16 %0, %1, %2" : "=v"(pa) : "v"(e1p2), "v"(epw[J]));   \
        asm("v_pk_mul_f16 %0, %1, %2" : "=v"(pb) : "v"(e1n2), "v"(enw[J]));   \
        asm("v_pk_max_f16 %0, %1, %2" : "=v"(pm) : "v"(pa), "v"(pb));         \
        uint32_t mb0, mb1;                                                    \
        asm("v_bfe_i32 %0, %1, " #B0 ", 1" : "=v"(mb0) : "v"(ms));            \
        asm("v_bfe_i32 %0, %1, " #B1 ", 1" : "=v"(mb1) : "v"(ms));            \
        r.u[J] = pm & ((mb0 & 0x0000FFFFu) | (mb1 & 0xFFFF0000u));            \
    }
    PAIR(0, 0, 1)
    PAIR(1, 2, 3)
    PAIR(2, 4, 5)
    PAIR(3, 6, 7)
#undef PAIR
    return r.v;
}

struct Pf {                          // rotation prefetch slot
    int4 hb0, hb1, hb2, hb3;         // 4 H B-fragments (f16, this wave's kk)
    uint32_t m0, m1;                 // adjacency mask words per row-group
};

__device__ __forceinline__ f16x8 as_f16x8(int4 v) {
    union { int4 i; f16x8 h; } c;
    c.i = v;
    return c.h;
}

// ---------------------------------------------------------------------------
// Flash attention v8: barrier-free main loop; head = bid&7 (XCD-local hTF).
// ep/en tables computed in a block prologue into LDS (deletes k_tables and
// 8KB/blk-tile of L2 traffic); 3-deep Pf rotation so every compute consumes
// loads issued ~2 compute-phases earlier (covers L2 latency).
__global__ __launch_bounds__(256, 3) void k_flash(
    const unsigned short* __restrict__ hTF, const float* __restrict__ s1,
    const float* __restrict__ s2, const uint32_t* __restrict__ s2mu,
    const uint32_t* __restrict__ bmT32, float* __restrict__ out)
{
    __shared__ uint32_t epL[3072];                   // 12 KB packed-f16 tables
    __shared__ uint32_t enL[3072];                   // 12 KB
    __shared__ float fs[128 * 20];                   // 10 KB epilogue scratch

    const int head = blockIdx.x & 7;                 // == XCD id (round-robin)
    const int rb = blockIdx.x >> 3;
    const int tid = threadIdx.x;
    const int w = tid >> 6, lane = tid & 63, r15 = lane & 15, g = lane >> 4;
    const int w01 = w & 1;                           // row half
    const int wk = w >> 1;                           // m half (kk)
    const int shg = g * 8;                           // mask bit offset

    // ---- prologue: build packed-f16 ep/en tables for this head in LDS ----
    const float s2mh = decf(s2mu[head]);
    {
        const float4* s2h = (const float4*)(s2 + head * N_NODES);
#pragma unroll
        for (int i0 = 0; i0 < 6; ++i0) {
            int i = tid + i0 * 256;                  // 1536 float4s
            float4 v = s2h[i];
            uint32_t p0 = f16b(exp2f((v.x - s2mh) * L2E));
            uint32_t p1 = f16b(exp2f((v.y - s2mh) * L2E));
            uint32_t p2 = f16b(exp2f((v.z - s2mh) * L2E));
            uint32_t p3 = f16b(exp2f((v.w - s2mh) * L2E));
            uint32_t n0 = f16b(exp2f(ALPHA * (v.x - s2mh) * L2E));
            uint32_t n1 = f16b(exp2f(ALPHA * (v.y - s2mh) * L2E));
            uint32_t n2 = f16b(exp2f(ALPHA * (v.z - s2mh) * L2E));
            uint32_t n3 = f16b(exp2f(ALPHA * (v.w - s2mh) * L2E));
            epL[2 * i] = p0 | (p1 << 16);
            epL[2 * i + 1] = p2 | (p3 << 16);
            enL[2 * i] = n0 | (n1 << 16);
            enL[2 * i + 1] = n2 | (n3 << 16);
        }
    }

    const int rA = rb * 64 + w01 * 32 + r15;
    const int rB = rA + 16;
    const float s1A = s1[head * N_NODES + rA];
    const float s1B = s1[head * N_NODES + rB];
    const float t0A = s1A + s2mh, t0B = s1B + s2mh;
    const float MrA = fmaxf(t0A, ALPHA * t0A);
    const float MrB = fmaxf(t0B, ALPHA * t0B);
    uint32_t E1pA2, E1nA2, E1pB2, E1nB2;
    {
        uint32_t a = f16b(exp2f((t0A - MrA) * L2E));
        uint32_t b = f16b(exp2f((ALPHA * t0A - MrA) * L2E));
        uint32_t c = f16b(exp2f((t0B - MrB) * L2E));
        uint32_t d = f16b(exp2f((ALPHA * t0B - MrB) * L2E));
        E1pA2 = a | (a << 16);
        E1nA2 = b | (b << 16);
        E1pB2 = c | (c << 16);
        E1nB2 = d | (d << 16);
    }

    const unsigned short* __restrict__ hbp =
        hTF + ((size_t)(head * 96) * 8 + wk * 4) * 512 + lane * 8;
    const uint32_t* __restrict__ epb = epL + wk * 16 + g * 4;
    const uint32_t* __restrict__ enb = enL + wk * 16 + g * 4;
    const size_t mbA = (size_t)rA * 2 + wk;          // + t*12288 per tile
    const size_t mbB = (size_t)rB * 2 + wk;

    f32x4 accA[4] = {}, accB[4] = {};
    f32x4 accSA = {}, accSB = {};
    const f16x8 vones = {(_Float16)1.0f, (_Float16)1.0f, (_Float16)1.0f,
                         (_Float16)1.0f, (_Float16)1.0f, (_Float16)1.0f,
                         (_Float16)1.0f, (_Float16)1.0f};

    __syncthreads();                                 // tables ready

    auto loadPf = [&](int t, Pf& P) {
        const unsigned short* hp = hbp + (size_t)t * 4096;
        P.hb0 = *(const int4*)(hp);
        P.hb1 = *(const int4*)(hp + 512);
        P.hb2 = *(const int4*)(hp + 1024);
        P.hb3 = *(const int4*)(hp + 1536);
        P.m0 = bmT32[mbA + (size_t)t * 12288];
        P.m1 = bmT32[mbB + (size_t)t * 12288];
    };
    auto compute = [&](int t, Pf& C) {
        int4 ep = *(const int4*)(epb + t * 32);      // LDS broadcast reads
        int4 en = *(const int4*)(enb + t * 32);
        f16x8 paA = mk_pa16(ep, en, E1pA2, E1nA2, C.m0 >> shg);
        f16x8 paB = mk_pa16(ep, en, E1pB2, E1nB2, C.m1 >> shg);
        accSA = MFMA16H(paA, vones, accSA);
        accSB = MFMA16H(paB, vones, accSB);
        f16x8 h0 = as_f16x8(C.hb0), h1 = as_f16x8(C.hb1);
        f16x8 h2 = as_f16x8(C.hb2), h3 = as_f16x8(C.hb3);
        accA[0] = MFMA16H(paA, h0, accA[0]);
        accB[0] = MFMA16H(paB, h0, accB[0]);
        accA[1] = MFMA16H(paA, h1, accA[1]);
        accB[1] = MFMA16H(paB, h1, accB[1]);
        accA[2] = MFMA16H(paA, h2, accA[2]);
        accB[2] = MFMA16H(paB, h2, accB[2]);
        accA[3] = MFMA16H(paA, h3, accA[3]);
        accB[3] = MFMA16H(paB, h3, accB[3]);
    };

    Pf P0, P1, P2;
    loadPf(0, P0);
    loadPf(1, P1);
    for (int t = 0; t < NTILES; t += 3) {
        loadPf(t + 2, P2);                           // t+2 <= 95 always
        compute(t, P0);
        loadPf(t + 3 < NTILES ? t + 3 : NTILES - 1, P0);
        compute(t + 1, P1);
        loadPf(t + 4 < NTILES ? t + 4 : NTILES - 1, P1);
        compute(t + 2, P2);
    }

    // ---- epilogue: combine the two m-half waves through LDS ----
    const int slot = w01 * 64 + lane;
    const int fcb = head * 64;
    const int nA = rb * 64 + w01 * 32 + g * 4;

    if (wk == 1) {
#pragma unroll
        for (int ct = 0; ct < 4; ++ct)
#pragma unroll
            for (int j = 0; j < 4; ++j) fs[slot * 20 + ct * 4 + j] = accA[ct][j];
#pragma unroll
        for (int j = 0; j < 4; ++j) fs[slot * 20 + 16 + j] = accSA[j];
    }
    __syncthreads();
    if (wk == 0) {
        float rinv[4];
#pragma unroll
        for (int j = 0; j < 4; ++j)
            rinv[j] = 1.0f / (accSA[j] + fs[slot * 20 + 16 + j]);
#pragma unroll
        for (int ct = 0; ct < 4; ++ct)
#pragma unroll
            for (int j = 0; j < 4; ++j) {
                float v = (accA[ct][j] + fs[slot * 20 + ct * 4 + j]) * rinv[j];
                v = (v > 0.f) ? v : (expf(v) - 1.f);
                out[(size_t)(nA + j) * 512 + fcb + ct * 16 + r15] = v;
            }
    }
    __syncthreads();
    if (wk == 1) {
#pragma unroll
        for (int ct = 0; ct < 4; ++ct)
#pragma unroll
            for (int j = 0; j < 4; ++j) fs[slot * 20 + ct * 4 + j] = accB[ct][j];
#pragma unroll
        for (int j = 0; j < 4; ++j) fs[slot * 20 + 16 + j] = accSB[j];
    }
    __syncthreads();
    if (wk == 0) {
        float rinv[4];
#pragma unroll
        for (int j = 0; j < 4; ++j)
            rinv[j] = 1.0f / (accSB[j] + fs[slot * 20 + 16 + j]);
#pragma unroll
        for (int ct = 0; ct < 4; ++ct)
#pragma unroll
            for (int j = 0; j < 4; ++j) {
                float v = (accB[ct][j] + fs[slot * 20 + ct * 4 + j]) * rinv[j];
                v = (v > 0.f) ? v : (expf(v) - 1.f);
                out[(size_t)(nA + 16 + j) * 512 + fcb + ct * 16 + r15] = v;
            }
    }
}

// ---------------------------------------------------------------------------
extern "C" void kernel_launch(void* const* d_in, const int* in_sizes, int n_in,
                              void* d_out, int out_size, void* d_ws, size_t ws_size,
                              hipStream_t stream)
{
    const float* x = (const float*)d_in[0];
    const int* adj = (const int*)d_in[1];
    const float* W = (const float*)d_in[2];
    const float* a1 = (const float*)d_in[3];
    const float* a2 = (const float*)d_in[4];
    float* out = (float*)d_out;

    char* ws = (char*)d_ws;
    size_t off = 0;
    auto take = [&](size_t bytes) {
        void* p = ws + off;
        off = (off + bytes + 255) & ~(size_t)255;
        return p;
    };
    unsigned short* xh   = (unsigned short*)take((size_t)N_NODES * IN_F * 2);
    unsigned short* xl   = (unsigned short*)take((size_t)N_NODES * IN_F * 2);
    unsigned short* wthF = (unsigned short*)take((size_t)512 * 512 * 2);
    unsigned short* wtlF = (unsigned short*)take((size_t)512 * 512 * 2);
    unsigned short* hTF  = (unsigned short*)take((size_t)NH * 64 * N_NODES * 2);
    float* s1  = (float*)take((size_t)NH * N_NODES * 4);
    float* s2  = (float*)take((size_t)NH * N_NODES * 4);
    uint32_t* s2mu = (uint32_t*)take(256);
    unsigned long long* bmT =
        (unsigned long long*)take((size_t)N_NODES * (N_NODES / 64) * 8);

    k_prep<<<dim3(5248), dim3(256), 0, stream>>>(
        x, xh, xl, W, wthF, wtlF, s2mu, adj, bmT);
    k_proj<<<dim3(NH * (N_NODES / 64)), dim3(256), 0, stream>>>(
        xh, xl, wthF, wtlF, a1, a2, s1, s2, s2mu, hTF);
    k_flash<<<dim3(NH * NTILES), dim3(256), 0, stream>>>(
        hTF, s1, s2, s2mu, (const uint32_t*)bmT, out);
}

// Round 10
// 165.923 us; speedup vs baseline: 1.3945x; 1.0163x over previous
//
#include <hip/hip_runtime.h>
#include <hip/hip_bf16.h>
#include <stdint.h>

#define N_NODES 6144
#define IN_F    512
#define OUT_F   64
#define NH      8
#define ALPHA   0.2f
#define L2E     1.4426950408889634f
#define NTILES  (N_NODES / 64)   // 96

typedef __attribute__((ext_vector_type(8))) short bf16x8;
typedef __attribute__((ext_vector_type(8))) _Float16 f16x8;
typedef __attribute__((ext_vector_type(4))) float f32x4;

#define MFMA16B(a, b, c) __builtin_amdgcn_mfma_f32_16x16x32_bf16(a, b, c, 0, 0, 0)
#define MFMA16H(a, b, c) __builtin_amdgcn_mfma_f32_16x16x32_f16(a, b, c, 0, 0, 0)

__device__ __forceinline__ unsigned short f2bf(float f) {
    uint32_t u = __float_as_uint(f);
    u += 0x7fffu + ((u >> 16) & 1u);     // round-to-nearest-even
    return (unsigned short)(u >> 16);
}
__device__ __forceinline__ float bf2f(unsigned short h) {
    return __uint_as_float(((uint32_t)h) << 16);
}
__device__ __forceinline__ unsigned short f16b(float f) {
    union { _Float16 h; unsigned short u; } c;
    c.h = (_Float16)f;
    return c.u;
}
// monotone float<->uint encoding for atomicMax on floats (any sign)
__device__ __forceinline__ uint32_t encf(float x) {
    int i = __float_as_int(x);
    return (i >= 0) ? ((uint32_t)i | 0x80000000u) : ~(uint32_t)i;
}
__device__ __forceinline__ float decf(uint32_t u) {
    int i = (u & 0x80000000u) ? (int)(u & 0x7FFFFFFFu) : ~(int)u;
    return __int_as_float(i);
}

// ---------------------------------------------------------------------------
// Fused prep: [0,2048)   pack_adj  (HBM long pole, launched first)
//             [2048,5120) convert_x
//             [5120,5248) convert_w (fragment-order) + s2mu init
__global__ __launch_bounds__(256) void k_prep(
    const float* __restrict__ x, unsigned short* __restrict__ xh,
    unsigned short* __restrict__ xl,
    const float* __restrict__ W, unsigned short* __restrict__ wthF,
    unsigned short* __restrict__ wtlF, uint32_t* __restrict__ s2mu,
    const int* __restrict__ adj, unsigned long long* __restrict__ bmT)
{
    const int bid = blockIdx.x;
    if (bid < 2048) {
        // ---- pack_adj: adj -> transposed bitmask bmT[cb][row] ----
        const int stride = 2048 * 256;
        for (int idx = bid * 256 + threadIdx.x; idx < N_NODES * N_NODES;
             idx += stride) {
            unsigned long long b = __ballot(adj[idx] > 0);
            if ((threadIdx.x & 63) == 0) {
                int r = idx / N_NODES;
                int cb = (idx % N_NODES) >> 6;
                bmT[(size_t)cb * N_NODES + r] = b;
            }
        }
    } else if (bid < 5120) {
        // ---- convert_x: f32 -> split bf16 (hi+lo), once for all heads ----
        int i = (bid - 2048) * 256 + threadIdx.x;    // per float4, 786432
        float4 v = ((const float4*)x)[i];
        float vv[4] = {v.x, v.y, v.z, v.w};
        unsigned short h4[4], l4[4];
#pragma unroll
        for (int c = 0; c < 4; ++c) {
            unsigned short hb = f2bf(vv[c]);
            h4[c] = hb;
            l4[c] = f2bf(vv[c] - bf2f(hb));
        }
        ((ushort4*)xh)[i] = make_ushort4(h4[0], h4[1], h4[2], h4[3]);
        ((ushort4*)xl)[i] = make_ushort4(l4[0], l4[1], l4[2], l4[3]);
    } else {
        // ---- convert_w -> MFMA-B-fragment order (hi+lo); init s2mu ----
        int tid = (bid - 5120) * 256 + threadIdx.x;  // 32768
        if (bid == 5120 && threadIdx.x < NH) s2mu[threadIdx.x] = 0u;
        int lane = tid & 63;
        int rest = tid >> 6;
        int ct = rest & 3;
        int i = (rest >> 2) & 15;
        int h = rest >> 6;
        int f = ct * 16 + (lane & 15);
        int k0 = i * 32 + (lane >> 4) * 8;
        unsigned short oh[8], ol[8];
#pragma unroll
        for (int e = 0; e < 8; ++e) {
            float wv = W[((size_t)h * IN_F + k0 + e) * OUT_F + f];
            unsigned short hb = f2bf(wv);
            oh[e] = hb;
            ol[e] = f2bf(wv - bf2f(hb));
        }
        ushort4* dh = (ushort4*)(wthF + (size_t)tid * 8);
        dh[0] = make_ushort4(oh[0], oh[1], oh[2], oh[3]);
        dh[1] = make_ushort4(oh[4], oh[5], oh[6], oh[7]);
        ushort4* dl = (ushort4*)(wtlF + (size_t)tid * 8);
        dl[0] = make_ushort4(ol[0], ol[1], ol[2], ol[3]);
        dl[1] = make_ushort4(ol[4], ol[5], ol[6], ol[7]);
    }
}

// ---------------------------------------------------------------------------
// Projection: h = x @ W (split-bf16, fragment-ordered W, fully coalesced);
// writes s1/s2, per-head s2max (atomicMax), and hTF (f16 MFMA-B-fragment
// order) via swizzled LDS transpose. head = bid&7 (XCD-local W fragments).
__global__ __launch_bounds__(256) void k_proj(
    const unsigned short* __restrict__ xh, const unsigned short* __restrict__ xl,
    const unsigned short* __restrict__ wthF, const unsigned short* __restrict__ wtlF,
    const float* __restrict__ a1, const float* __restrict__ a2,
    float* __restrict__ s1, float* __restrict__ s2,
    uint32_t* __restrict__ s2mu, unsigned short* __restrict__ hTF)
{
    __shared__ unsigned short hlds[64][64];          // 8 KB f16 tile, swizzled

    const int head = blockIdx.x & 7;
    const int rb = blockIdx.x >> 3;                  // 0..95
    const int w = threadIdx.x >> 6;
    const int lane = threadIdx.x & 63;
    const int r15 = lane & 15;
    const int g = lane >> 4;
    const int rowbase = rb * 64 + w * 16;
    const int rowA = rowbase + r15;

    f32x4 acc[4] = {};
    const unsigned short* xhp = xh + (size_t)rowA * IN_F + g * 8;
    const unsigned short* xlp = xl + (size_t)rowA * IN_F + g * 8;
    const unsigned short* wb = wthF + ((size_t)head * 16 * 4 * 64) * 8 + lane * 8;
    const unsigned short* wl = wtlF + ((size_t)head * 16 * 4 * 64) * 8 + lane * 8;

#pragma unroll 4
    for (int i = 0; i < 16; ++i) {
        const int k0 = i * 32;
        bf16x8 ah = *(const bf16x8*)(xhp + k0);
        bf16x8 al = *(const bf16x8*)(xlp + k0);
#pragma unroll
        for (int ct = 0; ct < 4; ++ct) {
            const size_t fo = (size_t)(i * 4 + ct) * 512;
            bf16x8 bh = *(const bf16x8*)(wb + fo);
            bf16x8 bl = *(const bf16x8*)(wl + fo);
            acc[ct] = MFMA16B(ah, bh, acc[ct]);
            acc[ct] = MFMA16B(ah, bl, acc[ct]);
            acc[ct] = MFMA16B(al, bh, acc[ct]);
        }
    }

    // ---- s1/s2 (dot over f) ----
    float a1v[4], a2v[4];
#pragma unroll
    for (int ct = 0; ct < 4; ++ct) {
        a1v[ct] = a1[head * 64 + ct * 16 + r15];
        a2v[ct] = a2[head * 64 + ct * 16 + r15];
    }
    float sp1[4] = {0, 0, 0, 0}, sp2[4] = {0, 0, 0, 0};
#pragma unroll
    for (int ct = 0; ct < 4; ++ct)
#pragma unroll
        for (int j = 0; j < 4; ++j) {
            sp1[j] += acc[ct][j] * a1v[ct];
            sp2[j] += acc[ct][j] * a2v[ct];
        }
#pragma unroll
    for (int d = 1; d < 16; d <<= 1) {
#pragma unroll
        for (int j = 0; j < 4; ++j) {
            sp1[j] += __shfl_xor(sp1[j], d);
            sp2[j] += __shfl_xor(sp2[j], d);
        }
    }
    if (r15 == 0) {
#pragma unroll
        for (int j = 0; j < 4; ++j) {
            int n = rowbase + g * 4 + j;
            s1[head * N_NODES + n] = sp1[j];
            s2[head * N_NODES + n] = sp2[j];
        }
    }
    {   // per-head s2 max: wave-reduce then one atomic
        float m = fmaxf(fmaxf(sp2[0], sp2[1]), fmaxf(sp2[2], sp2[3]));
        m = fmaxf(m, __shfl_xor(m, 16));
        m = fmaxf(m, __shfl_xor(m, 32));
        if (lane == 0) atomicMax(s2mu + head, encf(m));
    }

    // ---- stage f16 tile to LDS (chunk-XOR swizzle) ----
#pragma unroll
    for (int ct = 0; ct < 4; ++ct) {
        ushort4 pk;
        pk.x = f16b(acc[ct][0]);
        pk.y = f16b(acc[ct][1]);
        pk.z = f16b(acc[ct][2]);
        pk.w = f16b(acc[ct][3]);
        int f_l = ct * 16 + r15;
        int n0 = w * 16 + g * 4;
        int col = (((n0 >> 3) ^ (f_l & 7)) << 3) + (n0 & 7);
        *(ushort4*)&hlds[f_l][col] = pk;
    }
    __syncthreads();

    // ---- write MFMA-B fragments (f16) to hTF, coalesced ----
#pragma unroll
    for (int q = 0; q < 2; ++q) {
        int fid = 2 * w + q;                          // 0..7 = wk*4+ct
        int wk = fid >> 2, ct = fid & 3;
        int f_l = ct * 16 + (lane & 15);
        int nch = wk * 4 + (lane >> 4);
        int col = ((nch ^ (f_l & 7)) << 3);
        int4 v = *(const int4*)&hlds[f_l][col];
        size_t base = (((size_t)(head * 96 + rb)) * 8 + fid) * 512 + lane * 8;
        *(int4*)(hTF + base) = v;
    }
}

// ---------------------------------------------------------------------------
// packed-f16 P fragment: p2 = max(E1p2*ep2, E1n2*en2) masked via bfe sign-mask
__device__ __forceinline__ f16x8 mk_pa16(int4 ep, int4 en, uint32_t e1p2,
                                         uint32_t e1n2, uint32_t ms)
{
    const uint32_t epw[4] = {(uint32_t)ep.x, (uint32_t)ep.y, (uint32_t)ep.z,
                             (uint32_t)ep.w};
    const uint32_t enw[4] = {(uint32_t)en.x, (uint32_t)en.y, (uint32_t)en.z,
                             (uint32_t)en.w};
    union { uint32_t u[4]; f16x8 v; } r;
#define PAIR(J, B0, B1)                                                       \
    {                                                                         \
        uint32_t pa, pb, pm;                                                  \
        asm("v_pk_mul_f16 %0, %1, %2" : "=v"(pa) : "v"(e1p2), "v"(epw[J]));   \
        asm("v_pk_mul_f16 %0, %1, %2" : "=v"(pb) : "v"(e1n2), "v"(enw[J]));   \
        asm("v_pk_max_f16 %0, %1, %2" : "=v"(pm) : "v"(pa), "v"(pb));         \
        uint32_t mb0, mb1;                                                    \
        asm("v_bfe_i32 %0, %1, " #B0 ", 1" : "=v"(mb0) : "v"(ms));            \
        asm("v_bfe_i32 %0, %1, " #B1 ", 1" : "=v"(mb1) : "v"(ms));            \
        r.u[J] = pm & ((mb0 & 0x0000FFFFu) | (mb1 & 0xFFFF0000u));            \
    }
    PAIR(0, 0, 1)
    PAIR(1, 2, 3)
    PAIR(2, 4, 5)
    PAIR(3, 6, 7)
#undef PAIR
    return r.v;
}

struct Pf {                          // rotation prefetch slot
    int4 hb0, hb1, hb2, hb3;         // 4 H B-fragments (f16, this wave's kk)
    uint32_t m0, m1;                 // adjacency mask words per row-group
};

__device__ __forceinline__ f16x8 as_f16x8(int4 v) {
    union { int4 i; f16x8 h; } c;
    c.i = v;
    return c.h;
}

// ---------------------------------------------------------------------------
// Flash attention v9: barrier-free main loop; head = bid&7 (XCD-local hTF);
// LDS ep/en tables. Prefetch pinned with inline-asm global loads + counted
// s_waitcnt vmcnt(12) + sched_barrier(0) (T4; compiler was sinking the R8/R9
// source-level prefetch to the use sites). s_setprio around MFMA (T5).
__global__ __launch_bounds__(256, 3) void k_flash(
    const unsigned short* __restrict__ hTF, const float* __restrict__ s1,
    const float* __restrict__ s2, const uint32_t* __restrict__ s2mu,
    const uint32_t* __restrict__ bmT32, float* __restrict__ out)
{
    __shared__ uint32_t epL[3072];                   // 12 KB packed-f16 tables
    __shared__ uint32_t enL[3072];                   // 12 KB
    __shared__ float fs[128 * 20];                   // 10 KB epilogue scratch

    const int head = blockIdx.x & 7;                 // == XCD id (round-robin)
    const int rb = blockIdx.x >> 3;
    const int tid = threadIdx.x;
    const int w = tid >> 6, lane = tid & 63, r15 = lane & 15, g = lane >> 4;
    const int w01 = w & 1;                           // row half
    const int wk = w >> 1;                           // m half (kk)
    const int shg = g * 8;                           // mask bit offset

    // ---- prologue: build packed-f16 ep/en tables for this head in LDS ----
    const float s2mh = decf(s2mu[head]);
    {
        const float4* s2h = (const float4*)(s2 + head * N_NODES);
#pragma unroll
        for (int i0 = 0; i0 < 6; ++i0) {
            int i = tid + i0 * 256;                  // 1536 float4s
            float4 v = s2h[i];
            uint32_t p0 = f16b(exp2f((v.x - s2mh) * L2E));
            uint32_t p1 = f16b(exp2f((v.y - s2mh) * L2E));
            uint32_t p2 = f16b(exp2f((v.z - s2mh) * L2E));
            uint32_t p3 = f16b(exp2f((v.w - s2mh) * L2E));
            uint32_t n0 = f16b(exp2f(ALPHA * (v.x - s2mh) * L2E));
            uint32_t n1 = f16b(exp2f(ALPHA * (v.y - s2mh) * L2E));
            uint32_t n2 = f16b(exp2f(ALPHA * (v.z - s2mh) * L2E));
            uint32_t n3 = f16b(exp2f(ALPHA * (v.w - s2mh) * L2E));
            epL[2 * i] = p0 | (p1 << 16);
            epL[2 * i + 1] = p2 | (p3 << 16);
            enL[2 * i] = n0 | (n1 << 16);
            enL[2 * i + 1] = n2 | (n3 << 16);
        }
    }

    const int rA = rb * 64 + w01 * 32 + r15;
    const int rB = rA + 16;
    const float s1A = s1[head * N_NODES + rA];
    const float s1B = s1[head * N_NODES + rB];
    const float t0A = s1A + s2mh, t0B = s1B + s2mh;
    const float MrA = fmaxf(t0A, ALPHA * t0A);
    const float MrB = fmaxf(t0B, ALPHA * t0B);
    uint32_t E1pA2, E1nA2, E1pB2, E1nB2;
    {
        uint32_t a = f16b(exp2f((t0A - MrA) * L2E));
        uint32_t b = f16b(exp2f((ALPHA * t0A - MrA) * L2E));
        uint32_t c = f16b(exp2f((t0B - MrB) * L2E));
        uint32_t d = f16b(exp2f((ALPHA * t0B - MrB) * L2E));
        E1pA2 = a | (a << 16);
        E1nA2 = b | (b << 16);
        E1pB2 = c | (c << 16);
        E1nB2 = d | (d << 16);
    }

    const unsigned short* __restrict__ hbp =
        hTF + ((size_t)(head * 96) * 8 + wk * 4) * 512 + lane * 8;
    const uint32_t* __restrict__ epb = epL + wk * 16 + g * 4;
    const uint32_t* __restrict__ enb = enL + wk * 16 + g * 4;
    const uint32_t* __restrict__ bmA = bmT32 + (size_t)rA * 2 + wk;
    const uint32_t* __restrict__ bmB = bmT32 + (size_t)rB * 2 + wk;

    f32x4 accA[4] = {}, accB[4] = {};
    f32x4 accSA = {}, accSB = {};
    const f16x8 vones = {(_Float16)1.0f, (_Float16)1.0f, (_Float16)1.0f,
                         (_Float16)1.0f, (_Float16)1.0f, (_Float16)1.0f,
                         (_Float16)1.0f, (_Float16)1.0f};

    __syncthreads();                                 // tables ready

    // pinned prefetch: asm loads (order-preserving, cannot be sunk)
    auto loadPf = [&](int t, Pf& P) {
        const unsigned short* hp = hbp + (size_t)t * 4096;
        asm volatile("global_load_dwordx4 %0, %1, off"
                     : "=v"(P.hb0) : "v"(hp));
        asm volatile("global_load_dwordx4 %0, %1, off offset:1024"
                     : "=v"(P.hb1) : "v"(hp));
        asm volatile("global_load_dwordx4 %0, %1, off offset:2048"
                     : "=v"(P.hb2) : "v"(hp));
        asm volatile("global_load_dwordx4 %0, %1, off offset:3072"
                     : "=v"(P.hb3) : "v"(hp));
        const uint32_t* pa = bmA + (size_t)t * 12288;
        const uint32_t* pb = bmB + (size_t)t * 12288;
        asm volatile("global_load_dword %0, %1, off" : "=v"(P.m0) : "v"(pa));
        asm volatile("global_load_dword %0, %1, off" : "=v"(P.m1) : "v"(pb));
    };
    auto compute = [&](int t, Pf& C) {
        int4 ep = *(const int4*)(epb + t * 32);      // LDS broadcast reads
        int4 en = *(const int4*)(enb + t * 32);
        f16x8 paA = mk_pa16(ep, en, E1pA2, E1nA2, C.m0 >> shg);
        f16x8 paB = mk_pa16(ep, en, E1pB2, E1nB2, C.m1 >> shg);
        __builtin_amdgcn_s_setprio(1);
        accSA = MFMA16H(paA, vones, accSA);
        accSB = MFMA16H(paB, vones, accSB);
        f16x8 h0 = as_f16x8(C.hb0), h1 = as_f16x8(C.hb1);
        f16x8 h2 = as_f16x8(C.hb2), h3 = as_f16x8(C.hb3);
        accA[0] = MFMA16H(paA, h0, accA[0]);
        accB[0] = MFMA16H(paB, h0, accB[0]);
        accA[1] = MFMA16H(paA, h1, accA[1]);
        accB[1] = MFMA16H(paB, h1, accB[1]);
        accA[2] = MFMA16H(paA, h2, accA[2]);
        accB[2] = MFMA16H(paB, h2, accB[2]);
        accA[3] = MFMA16H(paA, h3, accA[3]);
        accB[3] = MFMA16H(paB, h3, accB[3]);
        __builtin_amdgcn_s_setprio(0);
    };

    Pf P0, P1, P2;
    loadPf(0, P0);
    loadPf(1, P1);
    loadPf(2, P2);                                   // 18 loads outstanding
    for (int t = 0; t < NTILES; t += 3) {
        // oldest Pf (6 loads) complete; 12 (2 Pf) stay in flight
        asm volatile("s_waitcnt vmcnt(12)");
        __builtin_amdgcn_sched_barrier(0);
        compute(t, P0);
        loadPf(t + 3 < NTILES ? t + 3 : NTILES - 1, P0);

        asm volatile("s_waitcnt vmcnt(12)");
        __builtin_amdgcn_sched_barrier(0);
        compute(t + 1, P1);
        loadPf(t + 4 < NTILES ? t + 4 : NTILES - 1, P1);

        asm volatile("s_waitcnt vmcnt(12)");
        __builtin_amdgcn_sched_barrier(0);
        compute(t + 2, P2);
        loadPf(t + 5 < NTILES ? t + 5 : NTILES - 1, P2);
    }
    // drain: in-flight tail loads still target P0-P2 registers
    asm volatile("s_waitcnt vmcnt(0)");
    __builtin_amdgcn_sched_barrier(0);

    // ---- epilogue: combine the two m-half waves through LDS ----
    const int slot = w01 * 64 + lane;
    const int fcb = head * 64;
    const int nA = rb * 64 + w01 * 32 + g * 4;

    if (wk == 1) {
#pragma unroll
        for (int ct = 0; ct < 4; ++ct)
#pragma unroll
            for (int j = 0; j < 4; ++j) fs[slot * 20 + ct * 4 + j] = accA[ct][j];
#pragma unroll
        for (int j = 0; j < 4; ++j) fs[slot * 20 + 16 + j] = accSA[j];
    }
    __syncthreads();
    if (wk == 0) {
        float rinv[4];
#pragma unroll
        for (int j = 0; j < 4; ++j)
            rinv[j] = 1.0f / (accSA[j] + fs[slot * 20 + 16 + j]);
#pragma unroll
        for (int ct = 0; ct < 4; ++ct)
#pragma unroll
            for (int j = 0; j < 4; ++j) {
                float v = (accA[ct][j] + fs[slot * 20 + ct * 4 + j]) * rinv[j];
                v = (v > 0.f) ? v : (expf(v) - 1.f);
                out[(size_t)(nA + j) * 512 + fcb + ct * 16 + r15] = v;
            }
    }
    __syncthreads();
    if (wk == 1) {
#pragma unroll
        for (int ct = 0; ct < 4; ++ct)
#pragma unroll
            for (int j = 0; j < 4; ++j) fs[slot * 20 + ct * 4 + j] = accB[ct][j];
#pragma unroll
        for (int j = 0; j < 4; ++j) fs[slot * 20 + 16 + j] = accSB[j];
    }
    __syncthreads();
    if (wk == 0) {
        float rinv[4];
#pragma unroll
        for (int j = 0; j < 4; ++j)
            rinv[j] = 1.0f / (accSB[j] + fs[slot * 20 + 16 + j]);
#pragma unroll
        for (int ct = 0; ct < 4; ++ct)
#pragma unroll
            for (int j = 0; j < 4; ++j) {
                float v = (accB[ct][j] + fs[slot * 20 + ct * 4 + j]) * rinv[j];
                v = (v > 0.f) ? v : (expf(v) - 1.f);
                out[(size_t)(nA + 16 + j) * 512 + fcb + ct * 16 + r15] = v;
            }
    }
}

// ---------------------------------------------------------------------------
extern "C" void kernel_launch(void* const* d_in, const int* in_sizes, int n_in,
                              void* d_out, int out_size, void* d_ws, size_t ws_size,
                              hipStream_t stream)
{
    const float* x = (const float*)d_in[0];
    const int* adj = (const int*)d_in[1];
    const float* W = (const float*)d_in[2];
    const float* a1 = (const float*)d_in[3];
    const float* a2 = (const float*)d_in[4];
    float* out = (float*)d_out;

    char* ws = (char*)d_ws;
    size_t off = 0;
    auto take = [&](size_t bytes) {
        void* p = ws + off;
        off = (off + bytes + 255) & ~(size_t)255;
        return p;
    };
    unsigned short* xh   = (unsigned short*)take((size_t)N_NODES * IN_F * 2);
    unsigned short* xl   = (unsigned short*)take((size_t)N_NODES * IN_F * 2);
    unsigned short* wthF = (unsigned short*)take((size_t)512 * 512 * 2);
    unsigned short* wtlF = (unsigned short*)take((size_t)512 * 512 * 2);
    unsigned short* hTF  = (unsigned short*)take((size_t)NH * 64 * N_NODES * 2);
    float* s1  = (float*)take((size_t)NH * N_NODES * 4);
    float* s2  = (float*)take((size_t)NH * N_NODES * 4);
    uint32_t* s2mu = (uint32_t*)take(256);
    unsigned long long* bmT =
        (unsigned long long*)take((size_t)N_NODES * (N_NODES / 64) * 8);

    k_prep<<<dim3(5248), dim3(256), 0, stream>>>(
        x, xh, xl, W, wthF, wtlF, s2mu, adj, bmT);
    k_proj<<<dim3(NH * (N_NODES / 64)), dim3(256), 0, stream>>>(
        xh, xl, wthF, wtlF, a1, a2, s1, s2, s2mu, hTF);
    k_flash<<<dim3(NH * NTILES), dim3(256), 0, stream>>>(
        hTF, s1, s2, s2mu, (const uint32_t*)bmT, out);
}

// Round 12
// 157.779 us; speedup vs baseline: 1.4665x; 1.0516x over previous
//
#include <hip/hip_runtime.h>
#include <hip/hip_bf16.h>
#include <stdint.h>

#define N_NODES 6144
#define IN_F    512
#define OUT_F   64
#define NH      8
#define ALPHA   0.2f
#define L2E     1.4426950408889634f
#define NTILES  (N_NODES / 64)   // 96

typedef __attribute__((ext_vector_type(8))) short bf16x8;
typedef __attribute__((ext_vector_type(8))) _Float16 f16x8;
typedef __attribute__((ext_vector_type(4))) float f32x4;

#define MFMA16B(a, b, c) __builtin_amdgcn_mfma_f32_16x16x32_bf16(a, b, c, 0, 0, 0)
#define MFMA16H(a, b, c) __builtin_amdgcn_mfma_f32_16x16x32_f16(a, b, c, 0, 0, 0)

__device__ __forceinline__ unsigned short f2bf(float f) {
    uint32_t u = __float_as_uint(f);
    u += 0x7fffu + ((u >> 16) & 1u);     // round-to-nearest-even
    return (unsigned short)(u >> 16);
}
__device__ __forceinline__ float bf2f(unsigned short h) {
    return __uint_as_float(((uint32_t)h) << 16);
}
__device__ __forceinline__ unsigned short f16b(float f) {
    union { _Float16 h; unsigned short u; } c;
    c.h = (_Float16)f;
    return c.u;
}
// monotone float<->uint encoding for atomicMax on floats (any sign)
__device__ __forceinline__ uint32_t encf(float x) {
    int i = __float_as_int(x);
    return (i >= 0) ? ((uint32_t)i | 0x80000000u) : ~(uint32_t)i;
}
__device__ __forceinline__ float decf(uint32_t u) {
    int i = (u & 0x80000000u) ? (int)(u & 0x7FFFFFFFu) : ~(int)u;
    return __int_as_float(i);
}

// ---------------------------------------------------------------------------
// Fused prep: [0,2048)   pack_adj  (chunked, coalesced read AND write)
//             [2048,5120) convert_x
//             [5120,5248) convert_w (fragment-order) + s2mu init
__global__ __launch_bounds__(256) void k_prep(
    const float* __restrict__ x, unsigned short* __restrict__ xh,
    unsigned short* __restrict__ xl,
    const float* __restrict__ W, unsigned short* __restrict__ wthF,
    unsigned short* __restrict__ wtlF, uint32_t* __restrict__ s2mu,
    const int* __restrict__ adj, unsigned long long* __restrict__ bmT)
{
    const int bid = blockIdx.x;
    if (bid < 2048) {
        // ---- pack_adj: wave owns (cb, 64-row) chunk -> bmT[cb][r] ----
        const int lane = threadIdx.x & 63;
        const int wgid = bid * 4 + (threadIdx.x >> 6);   // 0..8191
        for (int ch = wgid; ch < 96 * 96; ch += 8192) {
            const int cb = ch % 96, rblk = ch / 96;
            const int* ap = adj + (size_t)(rblk * 64) * N_NODES + cb * 64 + lane;
            unsigned long long keep = 0;
            for (int rr = 0; rr < 64; ++rr) {
                unsigned long long b = __ballot(ap[(size_t)rr * N_NODES] > 0);
                if (lane == rr) keep = b;                // b is wave-uniform
            }
            bmT[(size_t)cb * N_NODES + rblk * 64 + lane] = keep;  // 512B/wave
        }
    } else if (bid < 5120) {
        // ---- convert_x: f32 -> split bf16 (hi+lo), once for all heads ----
        int i = (bid - 2048) * 256 + threadIdx.x;    // per float4, 786432
        float4 v = ((const float4*)x)[i];
        float vv[4] = {v.x, v.y, v.z, v.w};
        unsigned short h4[4], l4[4];
#pragma unroll
        for (int c = 0; c < 4; ++c) {
            unsigned short hb = f2bf(vv[c]);
            h4[c] = hb;
            l4[c] = f2bf(vv[c] - bf2f(hb));
        }
        ((ushort4*)xh)[i] = make_ushort4(h4[0], h4[1], h4[2], h4[3]);
        ((ushort4*)xl)[i] = make_ushort4(l4[0], l4[1], l4[2], l4[3]);
    } else {
        // ---- convert_w -> MFMA-B-fragment order (hi+lo); init s2mu ----
        int tid = (bid - 5120) * 256 + threadIdx.x;  // 32768
        if (bid == 5120 && threadIdx.x < NH) s2mu[threadIdx.x] = 0u;
        int lane = tid & 63;
        int rest = tid >> 6;
        int ct = rest & 3;
        int i = (rest >> 2) & 15;
        int h = rest >> 6;
        int f = ct * 16 + (lane & 15);
        int k0 = i * 32 + (lane >> 4) * 8;
        unsigned short oh[8], ol[8];
#pragma unroll
        for (int e = 0; e < 8; ++e) {
            float wv = W[((size_t)h * IN_F + k0 + e) * OUT_F + f];
            unsigned short hb = f2bf(wv);
            oh[e] = hb;
            ol[e] = f2bf(wv - bf2f(hb));
        }
        ushort4* dh = (ushort4*)(wthF + (size_t)tid * 8);
        dh[0] = make_ushort4(oh[0], oh[1], oh[2], oh[3]);
        dh[1] = make_ushort4(oh[4], oh[5], oh[6], oh[7]);
        ushort4* dl = (ushort4*)(wtlF + (size_t)tid * 8);
        dl[0] = make_ushort4(ol[0], ol[1], ol[2], ol[3]);
        dl[1] = make_ushort4(ol[4], ol[5], ol[6], ol[7]);
    }
}

// ---------------------------------------------------------------------------
// Projection: h = x @ W (split-bf16, fragment-ordered W, fully coalesced);
// writes s1/s2, per-head s2max (atomicMax), and hTF (f16 MFMA-B-fragment
// order) via swizzled LDS transpose. head = bid&7 (XCD-local W fragments).
__global__ __launch_bounds__(256) void k_proj(
    const unsigned short* __restrict__ xh, const unsigned short* __restrict__ xl,
    const unsigned short* __restrict__ wthF, const unsigned short* __restrict__ wtlF,
    const float* __restrict__ a1, const float* __restrict__ a2,
    float* __restrict__ s1, float* __restrict__ s2,
    uint32_t* __restrict__ s2mu, unsigned short* __restrict__ hTF)
{
    __shared__ unsigned short hlds[64][64];          // 8 KB f16 tile, swizzled

    const int head = blockIdx.x & 7;
    const int rb = blockIdx.x >> 3;                  // 0..95
    const int w = threadIdx.x >> 6;
    const int lane = threadIdx.x & 63;
    const int r15 = lane & 15;
    const int g = lane >> 4;
    const int rowbase = rb * 64 + w * 16;
    const int rowA = rowbase + r15;

    f32x4 acc[4] = {};
    const unsigned short* xhp = xh + (size_t)rowA * IN_F + g * 8;
    const unsigned short* xlp = xl + (size_t)rowA * IN_F + g * 8;
    const unsigned short* wb = wthF + ((size_t)head * 16 * 4 * 64) * 8 + lane * 8;
    const unsigned short* wl = wtlF + ((size_t)head * 16 * 4 * 64) * 8 + lane * 8;

#pragma unroll 4
    for (int i = 0; i < 16; ++i) {
        const int k0 = i * 32;
        bf16x8 ah = *(const bf16x8*)(xhp + k0);
        bf16x8 al = *(const bf16x8*)(xlp + k0);
#pragma unroll
        for (int ct = 0; ct < 4; ++ct) {
            const size_t fo = (size_t)(i * 4 + ct) * 512;
            bf16x8 bh = *(const bf16x8*)(wb + fo);
            bf16x8 bl = *(const bf16x8*)(wl + fo);
            acc[ct] = MFMA16B(ah, bh, acc[ct]);
            acc[ct] = MFMA16B(ah, bl, acc[ct]);
            acc[ct] = MFMA16B(al, bh, acc[ct]);
        }
    }

    // ---- s1/s2 (dot over f) ----
    float a1v[4], a2v[4];
#pragma unroll
    for (int ct = 0; ct < 4; ++ct) {
        a1v[ct] = a1[head * 64 + ct * 16 + r15];
        a2v[ct] = a2[head * 64 + ct * 16 + r15];
    }
    float sp1[4] = {0, 0, 0, 0}, sp2[4] = {0, 0, 0, 0};
#pragma unroll
    for (int ct = 0; ct < 4; ++ct)
#pragma unroll
        for (int j = 0; j < 4; ++j) {
            sp1[j] += acc[ct][j] * a1v[ct];
            sp2[j] += acc[ct][j] * a2v[ct];
        }
#pragma unroll
    for (int d = 1; d < 16; d <<= 1) {
#pragma unroll
        for (int j = 0; j < 4; ++j) {
            sp1[j] += __shfl_xor(sp1[j], d);
            sp2[j] += __shfl_xor(sp2[j], d);
        }
    }
    if (r15 == 0) {
#pragma unroll
        for (int j = 0; j < 4; ++j) {
            int n = rowbase + g * 4 + j;
            s1[head * N_NODES + n] = sp1[j];
            s2[head * N_NODES + n] = sp2[j];
        }
    }
    {   // per-head s2 max: wave-reduce then one atomic
        float m = fmaxf(fmaxf(sp2[0], sp2[1]), fmaxf(sp2[2], sp2[3]));
        m = fmaxf(m, __shfl_xor(m, 16));
        m = fmaxf(m, __shfl_xor(m, 32));
        if (lane == 0) atomicMax(s2mu + head, encf(m));
    }

    // ---- stage f16 tile to LDS (chunk-XOR swizzle) ----
#pragma unroll
    for (int ct = 0; ct < 4; ++ct) {
        ushort4 pk;
        pk.x = f16b(acc[ct][0]);
        pk.y = f16b(acc[ct][1]);
        pk.z = f16b(acc[ct][2]);
        pk.w = f16b(acc[ct][3]);
        int f_l = ct * 16 + r15;
        int n0 = w * 16 + g * 4;
        int col = (((n0 >> 3) ^ (f_l & 7)) << 3) + (n0 & 7);
        *(ushort4*)&hlds[f_l][col] = pk;
    }
    __syncthreads();

    // ---- write MFMA-B fragments (f16) to hTF, coalesced ----
#pragma unroll
    for (int q = 0; q < 2; ++q) {
        int fid = 2 * w + q;                          // 0..7 = wk*4+ct
        int wk = fid >> 2, ct = fid & 3;
        int f_l = ct * 16 + (lane & 15);
        int nch = wk * 4 + (lane >> 4);
        int col = ((nch ^ (f_l & 7)) << 3);
        int4 v = *(const int4*)&hlds[f_l][col];
        size_t base = (((size_t)(head * 96 + rb)) * 8 + fid) * 512 + lane * 8;
        *(int4*)(hTF + base) = v;
    }
}

// ---------------------------------------------------------------------------
// packed-f16 P fragment: p2 = max(E1p2*ep2, E1n2*en2), mask via bfe + bfi
__device__ __forceinline__ f16x8 mk_pa16(int4 ep, int4 en, uint32_t e1p2,
                                         uint32_t e1n2, uint32_t ms,
                                         uint32_t kFFFF)
{
    const uint32_t epw[4] = {(uint32_t)ep.x, (uint32_t)ep.y, (uint32_t)ep.z,
                             (uint32_t)ep.w};
    const uint32_t enw[4] = {(uint32_t)en.x, (uint32_t)en.y, (uint32_t)en.z,
                             (uint32_t)en.w};
    union { uint32_t u[4]; f16x8 v; } r;
#define PAIR(J, B0, B1)                                                       \
    {                                                                         \
        uint32_t pa, pb, pm, mw;                                              \
        asm("v_pk_mul_f16 %0, %1, %2" : "=v"(pa) : "v"(e1p2), "v"(epw[J]));   \
        asm("v_pk_mul_f16 %0, %1, %2" : "=v"(pb) : "v"(e1n2), "v"(enw[J]));   \
        asm("v_pk_max_f16 %0, %1, %2" : "=v"(pm) : "v"(pa), "v"(pb));         \
        uint32_t mb0, mb1;                                                    \
        asm("v_bfe_i32 %0, %1, " #B0 ", 1" : "=v"(mb0) : "v"(ms));            \
        asm("v_bfe_i32 %0, %1, " #B1 ", 1" : "=v"(mb1) : "v"(ms));            \
        asm("v_bfi_b32 %0, %1, %2, %3"                                        \
            : "=v"(mw) : "s"(kFFFF), "v"(mb0), "v"(mb1));                     \
        r.u[J] = pm & mw;                                                     \
    }
    PAIR(0, 0, 1)
    PAIR(1, 2, 3)
    PAIR(2, 4, 5)
    PAIR(3, 6, 7)
#undef PAIR
    return r.v;
}

struct Pf {                          // rotation prefetch slot
    int4 hb0, hb1, hb2, hb3;         // 4 H B-fragments (f16, this wave's kk)
    uint32_t m0, m1;                 // adjacency mask words per row-group
};

__device__ __forceinline__ f16x8 as_f16x8(int4 v) {
    union { int4 i; f16x8 h; } c;
    c.i = v;
    return c.h;
}

// ---------------------------------------------------------------------------
// Flash attention v11: barrier-free; head = bid&7 (XCD-local hTF); LDS ep/en
// tables. Pinned 3-deep prefetch with 64-bit vaddr asm loads (R10's saddr
// form was illegal: bases are wave-uniform but not compiler-provably so) and
// INCREMENTING pointer registers (2 v_add per pointer per tile, no full
// rebuild). Unconditional tail prefetch into padded buffers; bfi mask merge.
__global__ __launch_bounds__(256, 3) void k_flash(
    const unsigned short* __restrict__ hTF, const float* __restrict__ s1,
    const float* __restrict__ s2, const uint32_t* __restrict__ s2mu,
    const uint32_t* __restrict__ bmT32, float* __restrict__ out)
{
    __shared__ uint32_t epL[3072];                   // 12 KB packed-f16 tables
    __shared__ uint32_t enL[3072];                   // 12 KB
    __shared__ float fs[128 * 20];                   // 10 KB epilogue scratch

    const int head = blockIdx.x & 7;                 // == XCD id (round-robin)
    const int rb = blockIdx.x >> 3;
    const int tid = threadIdx.x;
    const int w = tid >> 6, lane = tid & 63, r15 = lane & 15, g = lane >> 4;
    const int w01 = w & 1;                           // row half
    const int wk = w >> 1;                           // m half (kk)
    const int shg = g * 8;                           // mask bit offset
    const uint32_t kFFFF = 0xFFFFu;

    // ---- prologue: build packed-f16 ep/en tables for this head in LDS ----
    const float s2mh = decf(s2mu[head]);
    {
        const float4* s2h = (const float4*)(s2 + head * N_NODES);
#pragma unroll
        for (int i0 = 0; i0 < 6; ++i0) {
            int i = tid + i0 * 256;                  // 1536 float4s
            float4 v = s2h[i];
            uint32_t p0 = f16b(exp2f((v.x - s2mh) * L2E));
            uint32_t p1 = f16b(exp2f((v.y - s2mh) * L2E));
            uint32_t p2 = f16b(exp2f((v.z - s2mh) * L2E));
            uint32_t p3 = f16b(exp2f((v.w - s2mh) * L2E));
            uint32_t n0 = f16b(exp2f(ALPHA * (v.x - s2mh) * L2E));
            uint32_t n1 = f16b(exp2f(ALPHA * (v.y - s2mh) * L2E));
            uint32_t n2 = f16b(exp2f(ALPHA * (v.z - s2mh) * L2E));
            uint32_t n3 = f16b(exp2f(ALPHA * (v.w - s2mh) * L2E));
            epL[2 * i] = p0 | (p1 << 16);
            epL[2 * i + 1] = p2 | (p3 << 16);
            enL[2 * i] = n0 | (n1 << 16);
            enL[2 * i + 1] = n2 | (n3 << 16);
        }
    }

    const int rA = rb * 64 + w01 * 32 + r15;
    const int rB = rA + 16;
    const float s1A = s1[head * N_NODES + rA];
    const float s1B = s1[head * N_NODES + rB];
    const float t0A = s1A + s2mh, t0B = s1B + s2mh;
    const float MrA = fmaxf(t0A, ALPHA * t0A);
    const float MrB = fmaxf(t0B, ALPHA * t0B);
    uint32_t E1pA2, E1nA2, E1pB2, E1nB2;
    {
        uint32_t a = f16b(exp2f((t0A - MrA) * L2E));
        uint32_t b = f16b(exp2f((ALPHA * t0A - MrA) * L2E));
        uint32_t c = f16b(exp2f((t0B - MrB) * L2E));
        uint32_t d = f16b(exp2f((ALPHA * t0B - MrB) * L2E));
        E1pA2 = a | (a << 16);
        E1nA2 = b | (b << 16);
        E1pB2 = c | (c << 16);
        E1nB2 = d | (d << 16);
    }

    // incrementing 64-bit vaddr pointers (2 v_add per pointer per tile)
    const unsigned short* hp = hTF +
        ((size_t)(head * 96) * 8 + wk * 4) * 512 + lane * 8;
    const uint32_t* pa = bmT32 + (size_t)rA * 2 + wk;   // m1 = pa + 32 dwords

    const uint32_t* __restrict__ epb = epL + wk * 16 + g * 4;
    const uint32_t* __restrict__ enb = enL + wk * 16 + g * 4;

    f32x4 accA[4] = {}, accB[4] = {};
    f32x4 accSA = {}, accSB = {};
    const f16x8 vones = {(_Float16)1.0f, (_Float16)1.0f, (_Float16)1.0f,
                         (_Float16)1.0f, (_Float16)1.0f, (_Float16)1.0f,
                         (_Float16)1.0f, (_Float16)1.0f};

    __syncthreads();                                 // tables ready

    // pinned prefetch: vaddr asm loads (cannot be sunk); pointers advance
    auto loadPf = [&](Pf& P) {
        asm volatile("global_load_dwordx4 %0, %1, off"
                     : "=v"(P.hb0) : "v"(hp));
        asm volatile("global_load_dwordx4 %0, %1, off offset:1024"
                     : "=v"(P.hb1) : "v"(hp));
        asm volatile("global_load_dwordx4 %0, %1, off offset:2048"
                     : "=v"(P.hb2) : "v"(hp));
        asm volatile("global_load_dwordx4 %0, %1, off offset:3072"
                     : "=v"(P.hb3) : "v"(hp));
        asm volatile("global_load_dword %0, %1, off"
                     : "=v"(P.m0) : "v"(pa));
        asm volatile("global_load_dword %0, %1, off offset:128"
                     : "=v"(P.m1) : "v"(pa));
        hp += 4096;                                  // 8 KB / tile
        pa += 12288;                                 // 48 KB / tile
    };
    auto compute = [&](int t, Pf& C) {
        int4 ep = *(const int4*)(epb + t * 32);      // LDS broadcast reads
        int4 en = *(const int4*)(enb + t * 32);
        f16x8 paA = mk_pa16(ep, en, E1pA2, E1nA2, C.m0 >> shg, kFFFF);
        f16x8 paB = mk_pa16(ep, en, E1pB2, E1nB2, C.m1 >> shg, kFFFF);
        __builtin_amdgcn_s_setprio(1);
        accSA = MFMA16H(paA, vones, accSA);
        accSB = MFMA16H(paB, vones, accSB);
        f16x8 h0 = as_f16x8(C.hb0), h1 = as_f16x8(C.hb1);
        f16x8 h2 = as_f16x8(C.hb2), h3 = as_f16x8(C.hb3);
        accA[0] = MFMA16H(paA, h0, accA[0]);
        accB[0] = MFMA16H(paB, h0, accB[0]);
        accA[1] = MFMA16H(paA, h1, accA[1]);
        accB[1] = MFMA16H(paB, h1, accB[1]);
        accA[2] = MFMA16H(paA, h2, accA[2]);
        accB[2] = MFMA16H(paB, h2, accB[2]);
        accA[3] = MFMA16H(paA, h3, accA[3]);
        accB[3] = MFMA16H(paB, h3, accB[3]);
        __builtin_amdgcn_s_setprio(0);
    };

    Pf P0, P1, P2;
    loadPf(P0);
    loadPf(P1);
    loadPf(P2);                                      // 18 loads outstanding
    for (int t = 0; t < NTILES; t += 3) {
        // oldest Pf (6 loads) complete; 12 (2 Pf) stay in flight.
        // tail prefetches (t+3..98) read padded scratch - drained, unused.
        asm volatile("s_waitcnt vmcnt(12)");
        __builtin_amdgcn_sched_barrier(0);
        compute(t, P0);
        loadPf(P0);

        asm volatile("s_waitcnt vmcnt(12)");
        __builtin_amdgcn_sched_barrier(0);
        compute(t + 1, P1);
        loadPf(P1);

        asm volatile("s_waitcnt vmcnt(12)");
        __builtin_amdgcn_sched_barrier(0);
        compute(t + 2, P2);
        loadPf(P2);
    }
    // drain: in-flight tail loads still target P0-P2 registers
    asm volatile("s_waitcnt vmcnt(0)");
    __builtin_amdgcn_sched_barrier(0);

    // ---- epilogue: combine the two m-half waves through LDS ----
    const int slot = w01 * 64 + lane;
    const int fcb = head * 64;
    const int nA = rb * 64 + w01 * 32 + g * 4;

    if (wk == 1) {
#pragma unroll
        for (int ct = 0; ct < 4; ++ct)
#pragma unroll
            for (int j = 0; j < 4; ++j) fs[slot * 20 + ct * 4 + j] = accA[ct][j];
#pragma unroll
        for (int j = 0; j < 4; ++j) fs[slot * 20 + 16 + j] = accSA[j];
    }
    __syncthreads();
    if (wk == 0) {
        float rinv[4];
#pragma unroll
        for (int j = 0; j < 4; ++j)
            rinv[j] = 1.0f / (accSA[j] + fs[slot * 20 + 16 + j]);
#pragma unroll
        for (int ct = 0; ct < 4; ++ct)
#pragma unroll
            for (int j = 0; j < 4; ++j) {
                float v = (accA[ct][j] + fs[slot * 20 + ct * 4 + j]) * rinv[j];
                v = (v > 0.f) ? v : (expf(v) - 1.f);
                out[(size_t)(nA + j) * 512 + fcb + ct * 16 + r15] = v;
            }
    }
    __syncthreads();
    if (wk == 1) {
#pragma unroll
        for (int ct = 0; ct < 4; ++ct)
#pragma unroll
            for (int j = 0; j < 4; ++j) fs[slot * 20 + ct * 4 + j] = accB[ct][j];
#pragma unroll
        for (int j = 0; j < 4; ++j) fs[slot * 20 + 16 + j] = accSB[j];
    }
    __syncthreads();
    if (wk == 0) {
        float rinv[4];
#pragma unroll
        for (int j = 0; j < 4; ++j)
            rinv[j] = 1.0f / (accSB[j] + fs[slot * 20 + 16 + j]);
#pragma unroll
        for (int ct = 0; ct < 4; ++ct)
#pragma unroll
            for (int j = 0; j < 4; ++j) {
                float v = (accB[ct][j] + fs[slot * 20 + ct * 4 + j]) * rinv[j];
                v = (v > 0.f) ? v : (expf(v) - 1.f);
                out[(size_t)(nA + 16 + j) * 512 + fcb + ct * 16 + r15] = v;
            }
    }
}

// ---------------------------------------------------------------------------
extern "C" void kernel_launch(void* const* d_in, const int* in_sizes, int n_in,
                              void* d_out, int out_size, void* d_ws, size_t ws_size,
                              hipStream_t stream)
{
    const float* x = (const float*)d_in[0];
    const int* adj = (const int*)d_in[1];
    const float* W = (const float*)d_in[2];
    const float* a1 = (const float*)d_in[3];
    const float* a2 = (const float*)d_in[4];
    float* out = (float*)d_out;

    char* ws = (char*)d_ws;
    size_t off = 0;
    auto take = [&](size_t bytes) {
        void* p = ws + off;
        off = (off + bytes + 255) & ~(size_t)255;
        return p;
    };
    unsigned short* xh   = (unsigned short*)take((size_t)N_NODES * IN_F * 2);
    unsigned short* xl   = (unsigned short*)take((size_t)N_NODES * IN_F * 2);
    unsigned short* wthF = (unsigned short*)take((size_t)512 * 512 * 2);
    unsigned short* wtlF = (unsigned short*)take((size_t)512 * 512 * 2);
    // +32 KB slack: flash prefetches up to tile 98 (drained, never consumed)
    unsigned short* hTF  = (unsigned short*)take(
        (size_t)NH * 64 * N_NODES * 2 + 32768);
    float* s1  = (float*)take((size_t)NH * N_NODES * 4);
    float* s2  = (float*)take((size_t)NH * N_NODES * 4);
    uint32_t* s2mu = (uint32_t*)take(256);
    // +192 KB slack for the same tail prefetch
    unsigned long long* bmT = (unsigned long long*)take(
        (size_t)N_NODES * (N_NODES / 64) * 8 + 196608);

    k_prep<<<dim3(5248), dim3(256), 0, stream>>>(
        x, xh, xl, W, wthF, wtlF, s2mu, adj, bmT);
    k_proj<<<dim3(NH * (N_NODES / 64)), dim3(256), 0, stream>>>(
        xh, xl, wthF, wtlF, a1, a2, s1, s2, s2mu, hTF);
    k_flash<<<dim3(NH * NTILES), dim3(256), 0, stream>>>(
        hTF, s1, s2, s2mu, (const uint32_t*)bmT, out);
}

// Round 13
// 156.767 us; speedup vs baseline: 1.4759x; 1.0065x over previous
//
#include <hip/hip_runtime.h>
#include <hip/hip_bf16.h>
#include <stdint.h>

#define N_NODES 6144
#define IN_F    512
#define OUT_F   64
#define NH      8
#define ALPHA   0.2f
#define L2E     1.4426950408889634f
#define NTILES  (N_NODES / 64)   // 96

typedef __attribute__((ext_vector_type(8))) short bf16x8;
typedef __attribute__((ext_vector_type(8))) _Float16 f16x8;
typedef __attribute__((ext_vector_type(4))) float f32x4;

#define MFMA16B(a, b, c) __builtin_amdgcn_mfma_f32_16x16x32_bf16(a, b, c, 0, 0, 0)
#define MFMA16H(a, b, c) __builtin_amdgcn_mfma_f32_16x16x32_f16(a, b, c, 0, 0, 0)

__device__ __forceinline__ unsigned short f2bf(float f) {
    uint32_t u = __float_as_uint(f);
    u += 0x7fffu + ((u >> 16) & 1u);     // round-to-nearest-even
    return (unsigned short)(u >> 16);
}
__device__ __forceinline__ float bf2f(unsigned short h) {
    return __uint_as_float(((uint32_t)h) << 16);
}
__device__ __forceinline__ unsigned short f16b(float f) {
    union { _Float16 h; unsigned short u; } c;
    c.h = (_Float16)f;
    return c.u;
}
// monotone float<->uint encoding for atomicMax on floats (any sign)
__device__ __forceinline__ uint32_t encf(float x) {
    int i = __float_as_int(x);
    return (i >= 0) ? ((uint32_t)i | 0x80000000u) : ~(uint32_t)i;
}
__device__ __forceinline__ float decf(uint32_t u) {
    int i = (u & 0x80000000u) ? (int)(u & 0x7FFFFFFFu) : ~(int)u;
    return __int_as_float(i);
}

// ---------------------------------------------------------------------------
// Fused prep: [0,2048)   pack_adj  (chunked, coalesced read AND write)
//             [2048,5120) convert_x
//             [5120,5248) convert_w (fragment-order) + s2mu init
__global__ __launch_bounds__(256) void k_prep(
    const float* __restrict__ x, unsigned short* __restrict__ xh,
    unsigned short* __restrict__ xl,
    const float* __restrict__ W, unsigned short* __restrict__ wthF,
    unsigned short* __restrict__ wtlF, uint32_t* __restrict__ s2mu,
    const int* __restrict__ adj, unsigned long long* __restrict__ bmT)
{
    const int bid = blockIdx.x;
    if (bid < 2048) {
        // ---- pack_adj: wave owns (cb, 64-row) chunk -> bmT[cb][r] ----
        const int lane = threadIdx.x & 63;
        const int wgid = bid * 4 + (threadIdx.x >> 6);   // 0..8191
        for (int ch = wgid; ch < 96 * 96; ch += 8192) {
            const int cb = ch % 96, rblk = ch / 96;
            const int* ap = adj + (size_t)(rblk * 64) * N_NODES + cb * 64 + lane;
            unsigned long long keep = 0;
            for (int rr = 0; rr < 64; ++rr) {
                unsigned long long b = __ballot(ap[(size_t)rr * N_NODES] > 0);
                if (lane == rr) keep = b;                // b is wave-uniform
            }
            bmT[(size_t)cb * N_NODES + rblk * 64 + lane] = keep;  // 512B/wave
        }
    } else if (bid < 5120) {
        // ---- convert_x: f32 -> split bf16 (hi+lo), once for all heads ----
        int i = (bid - 2048) * 256 + threadIdx.x;    // per float4, 786432
        float4 v = ((const float4*)x)[i];
        float vv[4] = {v.x, v.y, v.z, v.w};
        unsigned short h4[4], l4[4];
#pragma unroll
        for (int c = 0; c < 4; ++c) {
            unsigned short hb = f2bf(vv[c]);
            h4[c] = hb;
            l4[c] = f2bf(vv[c] - bf2f(hb));
        }
        ((ushort4*)xh)[i] = make_ushort4(h4[0], h4[1], h4[2], h4[3]);
        ((ushort4*)xl)[i] = make_ushort4(l4[0], l4[1], l4[2], l4[3]);
    } else {
        // ---- convert_w -> MFMA-B-fragment order (hi+lo); init s2mu ----
        int tid = (bid - 5120) * 256 + threadIdx.x;  // 32768
        if (bid == 5120 && threadIdx.x < NH) s2mu[threadIdx.x] = 0u;
        int lane = tid & 63;
        int rest = tid >> 6;
        int ct = rest & 3;
        int i = (rest >> 2) & 15;
        int h = rest >> 6;
        int f = ct * 16 + (lane & 15);
        int k0 = i * 32 + (lane >> 4) * 8;
        unsigned short oh[8], ol[8];
#pragma unroll
        for (int e = 0; e < 8; ++e) {
            float wv = W[((size_t)h * IN_F + k0 + e) * OUT_F + f];
            unsigned short hb = f2bf(wv);
            oh[e] = hb;
            ol[e] = f2bf(wv - bf2f(hb));
        }
        ushort4* dh = (ushort4*)(wthF + (size_t)tid * 8);
        dh[0] = make_ushort4(oh[0], oh[1], oh[2], oh[3]);
        dh[1] = make_ushort4(oh[4], oh[5], oh[6], oh[7]);
        ushort4* dl = (ushort4*)(wtlF + (size_t)tid * 8);
        dl[0] = make_ushort4(ol[0], ol[1], ol[2], ol[3]);
        dl[1] = make_ushort4(ol[4], ol[5], ol[6], ol[7]);
    }
}

// ---------------------------------------------------------------------------
// Projection: h = x @ W (split-bf16, fragment-ordered W, fully coalesced);
// writes s1/s2, per-head s2max (atomicMax), and hTF (f16 MFMA-B-fragment
// order) via swizzled LDS transpose. head = bid&7 (XCD-local W fragments).
__global__ __launch_bounds__(256) void k_proj(
    const unsigned short* __restrict__ xh, const unsigned short* __restrict__ xl,
    const unsigned short* __restrict__ wthF, const unsigned short* __restrict__ wtlF,
    const float* __restrict__ a1, const float* __restrict__ a2,
    float* __restrict__ s1, float* __restrict__ s2,
    uint32_t* __restrict__ s2mu, unsigned short* __restrict__ hTF)
{
    __shared__ unsigned short hlds[64][64];          // 8 KB f16 tile, swizzled

    const int head = blockIdx.x & 7;
    const int rb = blockIdx.x >> 3;                  // 0..95
    const int w = threadIdx.x >> 6;
    const int lane = threadIdx.x & 63;
    const int r15 = lane & 15;
    const int g = lane >> 4;
    const int rowbase = rb * 64 + w * 16;
    const int rowA = rowbase + r15;

    f32x4 acc[4] = {};
    const unsigned short* xhp = xh + (size_t)rowA * IN_F + g * 8;
    const unsigned short* xlp = xl + (size_t)rowA * IN_F + g * 8;
    const unsigned short* wb = wthF + ((size_t)head * 16 * 4 * 64) * 8 + lane * 8;
    const unsigned short* wl = wtlF + ((size_t)head * 16 * 4 * 64) * 8 + lane * 8;

#pragma unroll 4
    for (int i = 0; i < 16; ++i) {
        const int k0 = i * 32;
        bf16x8 ah = *(const bf16x8*)(xhp + k0);
        bf16x8 al = *(const bf16x8*)(xlp + k0);
#pragma unroll
        for (int ct = 0; ct < 4; ++ct) {
            const size_t fo = (size_t)(i * 4 + ct) * 512;
            bf16x8 bh = *(const bf16x8*)(wb + fo);
            bf16x8 bl = *(const bf16x8*)(wl + fo);
            acc[ct] = MFMA16B(ah, bh, acc[ct]);
            acc[ct] = MFMA16B(ah, bl, acc[ct]);
            acc[ct] = MFMA16B(al, bh, acc[ct]);
        }
    }

    // ---- s1/s2 (dot over f) ----
    float a1v[4], a2v[4];
#pragma unroll
    for (int ct = 0; ct < 4; ++ct) {
        a1v[ct] = a1[head * 64 + ct * 16 + r15];
        a2v[ct] = a2[head * 64 + ct * 16 + r15];
    }
    float sp1[4] = {0, 0, 0, 0}, sp2[4] = {0, 0, 0, 0};
#pragma unroll
    for (int ct = 0; ct < 4; ++ct)
#pragma unroll
        for (int j = 0; j < 4; ++j) {
            sp1[j] += acc[ct][j] * a1v[ct];
            sp2[j] += acc[ct][j] * a2v[ct];
        }
#pragma unroll
    for (int d = 1; d < 16; d <<= 1) {
#pragma unroll
        for (int j = 0; j < 4; ++j) {
            sp1[j] += __shfl_xor(sp1[j], d);
            sp2[j] += __shfl_xor(sp2[j], d);
        }
    }
    if (r15 == 0) {
#pragma unroll
        for (int j = 0; j < 4; ++j) {
            int n = rowbase + g * 4 + j;
            s1[head * N_NODES + n] = sp1[j];
            s2[head * N_NODES + n] = sp2[j];
        }
    }
    {   // per-head s2 max: wave-reduce then one atomic
        float m = fmaxf(fmaxf(sp2[0], sp2[1]), fmaxf(sp2[2], sp2[3]));
        m = fmaxf(m, __shfl_xor(m, 16));
        m = fmaxf(m, __shfl_xor(m, 32));
        if (lane == 0) atomicMax(s2mu + head, encf(m));
    }

    // ---- stage f16 tile to LDS (chunk-XOR swizzle) ----
#pragma unroll
    for (int ct = 0; ct < 4; ++ct) {
        ushort4 pk;
        pk.x = f16b(acc[ct][0]);
        pk.y = f16b(acc[ct][1]);
        pk.z = f16b(acc[ct][2]);
        pk.w = f16b(acc[ct][3]);
        int f_l = ct * 16 + r15;
        int n0 = w * 16 + g * 4;
        int col = (((n0 >> 3) ^ (f_l & 7)) << 3) + (n0 & 7);
        *(ushort4*)&hlds[f_l][col] = pk;
    }
    __syncthreads();

    // ---- write MFMA-B fragments (f16) to hTF, coalesced ----
#pragma unroll
    for (int q = 0; q < 2; ++q) {
        int fid = 2 * w + q;                          // 0..7 = wk*4+ct
        int wk = fid >> 2, ct = fid & 3;
        int f_l = ct * 16 + (lane & 15);
        int nch = wk * 4 + (lane >> 4);
        int col = ((nch ^ (f_l & 7)) << 3);
        int4 v = *(const int4*)&hlds[f_l][col];
        size_t base = (((size_t)(head * 96 + rb)) * 8 + fid) * 512 + lane * 8;
        *(int4*)(hTF + base) = v;
    }
}

// ---------------------------------------------------------------------------
// packed-f16 P fragment: p2 = max(E1p2*ep2, E1n2*en2), mask via bfe + bfi
__device__ __forceinline__ f16x8 mk_pa16(int4 ep, int4 en, uint32_t e1p2,
                                         uint32_t e1n2, uint32_t ms,
                                         uint32_t kFFFF)
{
    const uint32_t epw[4] = {(uint32_t)ep.x, (uint32_t)ep.y, (uint32_t)ep.z,
                             (uint32_t)ep.w};
    const uint32_t enw[4] = {(uint32_t)en.x, (uint32_t)en.y, (uint32_t)en.z,
                             (uint32_t)en.w};
    union { uint32_t u[4]; f16x8 v; } r;
#define PAIR(J, B0, B1)                                                       \
    {                                                                         \
        uint32_t pa, pb, pm, mw;                                              \
        asm("v_pk_mul_f16 %0, %1, %2" : "=v"(pa) : "v"(e1p2), "v"(epw[J]));   \
        asm("v_pk_mul_f16 %0, %1, %2" : "=v"(pb) : "v"(e1n2), "v"(enw[J]));   \
        asm("v_pk_max_f16 %0, %1, %2" : "=v"(pm) : "v"(pa), "v"(pb));         \
        uint32_t mb0, mb1;                                                    \
        asm("v_bfe_i32 %0, %1, " #B0 ", 1" : "=v"(mb0) : "v"(ms));            \
        asm("v_bfe_i32 %0, %1, " #B1 ", 1" : "=v"(mb1) : "v"(ms));            \
        asm("v_bfi_b32 %0, %1, %2, %3"                                        \
            : "=v"(mw) : "s"(kFFFF), "v"(mb0), "v"(mb1));                     \
        r.u[J] = pm & mw;                                                     \
    }
    PAIR(0, 0, 1)
    PAIR(1, 2, 3)
    PAIR(2, 4, 5)
    PAIR(3, 6, 7)
#undef PAIR
    return r.v;
}

struct Ph {                          // hb rotation slot (3-deep, L2-latency)
    int4 hb0, hb1, hb2, hb3;         // 4 H B-fragments (f16, this wave's kk)
};
struct Pm {                          // mask rotation slot (6-deep, HBM-latency)
    uint32_t m0, m1;                 // adjacency mask words per row-group
};

__device__ __forceinline__ f16x8 as_f16x8(int4 v) {
    union { int4 i; f16x8 h; } c;
    c.i = v;
    return c.h;
}

// ---------------------------------------------------------------------------
// Flash attention v12: barrier-free; head = bid&7 (XCD-local hTF); LDS ep/en
// tables. SPLIT-DEPTH pinned prefetch: hb fragments 3-deep (L2-resident,
// ~200cy), adjacency masks 6-deep (streamed once per head -> L3/HBM,
// ~600-900cy). Per phase: [4x hb(t+3)][2x mask(t+6)]; wait vmcnt(14)
// guarantees hb(t) AND mask(t) complete (mask(t) is older in queue).
__global__ __launch_bounds__(256, 3) void k_flash(
    const unsigned short* __restrict__ hTF, const float* __restrict__ s1,
    const float* __restrict__ s2, const uint32_t* __restrict__ s2mu,
    const uint32_t* __restrict__ bmT32, float* __restrict__ out)
{
    __shared__ uint32_t epL[3072];                   // 12 KB packed-f16 tables
    __shared__ uint32_t enL[3072];                   // 12 KB
    __shared__ float fs[128 * 20];                   // 10 KB epilogue scratch

    const int head = blockIdx.x & 7;                 // == XCD id (round-robin)
    const int rb = blockIdx.x >> 3;
    const int tid = threadIdx.x;
    const int w = tid >> 6, lane = tid & 63, r15 = lane & 15, g = lane >> 4;
    const int w01 = w & 1;                           // row half
    const int wk = w >> 1;                           // m half (kk)
    const int shg = g * 8;                           // mask bit offset
    const uint32_t kFFFF = 0xFFFFu;

    // ---- prologue: build packed-f16 ep/en tables for this head in LDS ----
    const float s2mh = decf(s2mu[head]);
    {
        const float4* s2h = (const float4*)(s2 + head * N_NODES);
#pragma unroll
        for (int i0 = 0; i0 < 6; ++i0) {
            int i = tid + i0 * 256;                  // 1536 float4s
            float4 v = s2h[i];
            uint32_t p0 = f16b(exp2f((v.x - s2mh) * L2E));
            uint32_t p1 = f16b(exp2f((v.y - s2mh) * L2E));
            uint32_t p2 = f16b(exp2f((v.z - s2mh) * L2E));
            uint32_t p3 = f16b(exp2f((v.w - s2mh) * L2E));
            uint32_t n0 = f16b(exp2f(ALPHA * (v.x - s2mh) * L2E));
            uint32_t n1 = f16b(exp2f(ALPHA * (v.y - s2mh) * L2E));
            uint32_t n2 = f16b(exp2f(ALPHA * (v.z - s2mh) * L2E));
            uint32_t n3 = f16b(exp2f(ALPHA * (v.w - s2mh) * L2E));
            epL[2 * i] = p0 | (p1 << 16);
            epL[2 * i + 1] = p2 | (p3 << 16);
            enL[2 * i] = n0 | (n1 << 16);
            enL[2 * i + 1] = n2 | (n3 << 16);
        }
    }

    const int rA = rb * 64 + w01 * 32 + r15;
    const int rB = rA + 16;
    const float s1A = s1[head * N_NODES + rA];
    const float s1B = s1[head * N_NODES + rB];
    const float t0A = s1A + s2mh, t0B = s1B + s2mh;
    const float MrA = fmaxf(t0A, ALPHA * t0A);
    const float MrB = fmaxf(t0B, ALPHA * t0B);
    uint32_t E1pA2, E1nA2, E1pB2, E1nB2;
    {
        uint32_t a = f16b(exp2f((t0A - MrA) * L2E));
        uint32_t b = f16b(exp2f((ALPHA * t0A - MrA) * L2E));
        uint32_t c = f16b(exp2f((t0B - MrB) * L2E));
        uint32_t d = f16b(exp2f((ALPHA * t0B - MrB) * L2E));
        E1pA2 = a | (a << 16);
        E1nA2 = b | (b << 16);
        E1pB2 = c | (c << 16);
        E1nB2 = d | (d << 16);
    }

    // incrementing 64-bit vaddr pointers
    const unsigned short* hp = hTF +
        ((size_t)(head * 96) * 8 + wk * 4) * 512 + lane * 8;
    const uint32_t* pa = bmT32 + (size_t)rA * 2 + wk;   // rB mask at +128 B

    const uint32_t* __restrict__ epb = epL + wk * 16 + g * 4;
    const uint32_t* __restrict__ enb = enL + wk * 16 + g * 4;

    f32x4 accA[4] = {}, accB[4] = {};
    f32x4 accSA = {}, accSB = {};
    const f16x8 vones = {(_Float16)1.0f, (_Float16)1.0f, (_Float16)1.0f,
                         (_Float16)1.0f, (_Float16)1.0f, (_Float16)1.0f,
                         (_Float16)1.0f, (_Float16)1.0f};

    __syncthreads();                                 // tables ready

    auto loadH = [&](Ph& P) {
        asm volatile("global_load_dwordx4 %0, %1, off"
                     : "=v"(P.hb0) : "v"(hp));
        asm volatile("global_load_dwordx4 %0, %1, off offset:1024"
                     : "=v"(P.hb1) : "v"(hp));
        asm volatile("global_load_dwordx4 %0, %1, off offset:2048"
                     : "=v"(P.hb2) : "v"(hp));
        asm volatile("global_load_dwordx4 %0, %1, off offset:3072"
                     : "=v"(P.hb3) : "v"(hp));
        hp += 4096;                                  // 8 KB / tile
    };
    auto loadM = [&](Pm& P) {
        asm volatile("global_load_dword %0, %1, off"
                     : "=v"(P.m0) : "v"(pa));
        asm volatile("global_load_dword %0, %1, off offset:128"
                     : "=v"(P.m1) : "v"(pa));
        pa += 12288;                                 // 48 KB / tile
    };
    auto compute = [&](int t, Ph& H, Pm& M) {
        int4 ep = *(const int4*)(epb + t * 32);      // LDS broadcast reads
        int4 en = *(const int4*)(enb + t * 32);
        f16x8 paA = mk_pa16(ep, en, E1pA2, E1nA2, M.m0 >> shg, kFFFF);
        f16x8 paB = mk_pa16(ep, en, E1pB2, E1nB2, M.m1 >> shg, kFFFF);
        __builtin_amdgcn_s_setprio(1);
        accSA = MFMA16H(paA, vones, accSA);
        accSB = MFMA16H(paB, vones, accSB);
        f16x8 h0 = as_f16x8(H.hb0), h1 = as_f16x8(H.hb1);
        f16x8 h2 = as_f16x8(H.hb2), h3 = as_f16x8(H.hb3);
        accA[0] = MFMA16H(paA, h0, accA[0]);
        accB[0] = MFMA16H(paB, h0, accB[0]);
        accA[1] = MFMA16H(paA, h1, accA[1]);
        accB[1] = MFMA16H(paB, h1, accB[1]);
        accA[2] = MFMA16H(paA, h2, accA[2]);
        accB[2] = MFMA16H(paB, h2, accB[2]);
        accA[3] = MFMA16H(paA, h3, accA[3]);
        accB[3] = MFMA16H(paB, h3, accB[3]);
        __builtin_amdgcn_s_setprio(0);
    };

    Ph H0, H1, H2;
    Pm M0, M1, M2, M3, M4, M5;
    // prologue queue: m0,m1,m2 | h0,m3 | h1,m4 | h2,m5  (24 loads out)
    loadM(M0);
    loadM(M1);
    loadM(M2);
    loadH(H0);
    loadM(M3);
    loadH(H1);
    loadM(M4);
    loadH(H2);
    loadM(M5);

#define PHASE(K, HH, MM)                                                      \
    asm volatile("s_waitcnt vmcnt(14)");                                      \
    __builtin_amdgcn_sched_barrier(0);                                        \
    compute(t + K, HH, MM);                                                   \
    loadH(HH);                                                                \
    loadM(MM);

    for (int t = 0; t < NTILES; t += 6) {
        PHASE(0, H0, M0)
        PHASE(1, H1, M1)
        PHASE(2, H2, M2)
        PHASE(3, H0, M3)
        PHASE(4, H1, M4)
        PHASE(5, H2, M5)
    }
#undef PHASE
    // drain: in-flight tail loads still target H/M registers
    asm volatile("s_waitcnt vmcnt(0)");
    __builtin_amdgcn_sched_barrier(0);

    // ---- epilogue: combine the two m-half waves through LDS ----
    const int slot = w01 * 64 + lane;
    const int fcb = head * 64;
    const int nA = rb * 64 + w01 * 32 + g * 4;

    if (wk == 1) {
#pragma unroll
        for (int ct = 0; ct < 4; ++ct)
#pragma unroll
            for (int j = 0; j < 4; ++j) fs[slot * 20 + ct * 4 + j] = accA[ct][j];
#pragma unroll
        for (int j = 0; j < 4; ++j) fs[slot * 20 + 16 + j] = accSA[j];
    }
    __syncthreads();
    if (wk == 0) {
        float rinv[4];
#pragma unroll
        for (int j = 0; j < 4; ++j)
            rinv[j] = 1.0f / (accSA[j] + fs[slot * 20 + 16 + j]);
#pragma unroll
        for (int ct = 0; ct < 4; ++ct)
#pragma unroll
            for (int j = 0; j < 4; ++j) {
                float v = (accA[ct][j] + fs[slot * 20 + ct * 4 + j]) * rinv[j];
                v = (v > 0.f) ? v : (expf(v) - 1.f);
                out[(size_t)(nA + j) * 512 + fcb + ct * 16 + r15] = v;
            }
    }
    __syncthreads();
    if (wk == 1) {
#pragma unroll
        for (int ct = 0; ct < 4; ++ct)
#pragma unroll
            for (int j = 0; j < 4; ++j) fs[slot * 20 + ct * 4 + j] = accB[ct][j];
#pragma unroll
        for (int j = 0; j < 4; ++j) fs[slot * 20 + 16 + j] = accSB[j];
    }
    __syncthreads();
    if (wk == 0) {
        float rinv[4];
#pragma unroll
        for (int j = 0; j < 4; ++j)
            rinv[j] = 1.0f / (accSB[j] + fs[slot * 20 + 16 + j]);
#pragma unroll
        for (int ct = 0; ct < 4; ++ct)
#pragma unroll
            for (int j = 0; j < 4; ++j) {
                float v = (accB[ct][j] + fs[slot * 20 + ct * 4 + j]) * rinv[j];
                v = (v > 0.f) ? v : (expf(v) - 1.f);
                out[(size_t)(nA + 16 + j) * 512 + fcb + ct * 16 + r15] = v;
            }
    }
}

// ---------------------------------------------------------------------------
extern "C" void kernel_launch(void* const* d_in, const int* in_sizes, int n_in,
                              void* d_out, int out_size, void* d_ws, size_t ws_size,
                              hipStream_t stream)
{
    const float* x = (const float*)d_in[0];
    const int* adj = (const int*)d_in[1];
    const float* W = (const float*)d_in[2];
    const float* a1 = (const float*)d_in[3];
    const float* a2 = (const float*)d_in[4];
    float* out = (float*)d_out;

    char* ws = (char*)d_ws;
    size_t off = 0;
    auto take = [&](size_t bytes) {
        void* p = ws + off;
        off = (off + bytes + 255) & ~(size_t)255;
        return p;
    };
    unsigned short* xh   = (unsigned short*)take((size_t)N_NODES * IN_F * 2);
    unsigned short* xl   = (unsigned short*)take((size_t)N_NODES * IN_F * 2);
    unsigned short* wthF = (unsigned short*)take((size_t)512 * 512 * 2);
    unsigned short* wtlF = (unsigned short*)take((size_t)512 * 512 * 2);
    // +32 KB slack: flash prefetches hb up to tile 98 (drained, unused)
    unsigned short* hTF  = (unsigned short*)take(
        (size_t)NH * 64 * N_NODES * 2 + 32768);
    float* s1  = (float*)take((size_t)NH * N_NODES * 4);
    float* s2  = (float*)take((size_t)NH * N_NODES * 4);
    uint32_t* s2mu = (uint32_t*)take(256);
    // +384 KB slack: mask prefetch reaches tile 101 (drained, unused)
    unsigned long long* bmT = (unsigned long long*)take(
        (size_t)N_NODES * (N_NODES / 64) * 8 + 393216);

    k_prep<<<dim3(5248), dim3(256), 0, stream>>>(
        x, xh, xl, W, wthF, wtlF, s2mu, adj, bmT);
    k_proj<<<dim3(NH * (N_NODES / 64)), dim3(256), 0, stream>>>(
        xh, xl, wthF, wtlF, a1, a2, s1, s2, s2mu, hTF);
    k_flash<<<dim3(NH * NTILES), dim3(256), 0, stream>>>(
        hTF, s1, s2, s2mu, (const uint32_t*)bmT, out);
}